// Round 1
// 8027.266 us; speedup vs baseline: 1.1337x; 1.1337x over previous
//
#include <hip/hip_runtime.h>
#include <hip/hip_bf16.h>

#define VV 30000
#define HH 512
#define NC 9
#define BB 128
#define TT 256
#define GG 2048
#define TB (TT*BB)

using short8 = __attribute__((ext_vector_type(8))) short;
using f32x4  = __attribute__((ext_vector_type(4))) float;

__device__ inline float bf2f(unsigned short u){
    union { unsigned int i; float f; } v; v.i = ((unsigned int)u) << 16; return v.f;
}
__device__ inline unsigned short f2bf(float f){
    union { unsigned int i; float f; } v; v.f = f;
    unsigned int x = v.i;
    unsigned int r = (x + 0x7fffu + ((x >> 16) & 1u)) >> 16;
    return (unsigned short)r;
}
__device__ inline float sigm(float x){
    if (x >= 0.f){ return 1.f / (1.f + __expf(-x)); }
    float e = __expf(x); return e / (1.f + e);
}
__device__ inline float tanh_f(float x){
    float ax = fabsf(x);
    float e = __expf(-2.f * ax);
    float t = (1.f - e) / (1.f + e);
    return copysignf(t, x);
}

// ---------------- weight cast fp32 -> bf16 ----------------
__global__ void castbf(const float* __restrict__ in, unsigned short* __restrict__ out, int n){
    int i = blockIdx.x * blockDim.x + threadIdx.x;
    if (i < n) out[i] = f2bf(in[i]);
}

// ---------------- embedding + renorm -> xs bf16 [T*B][H] ----------------
__global__ __launch_bounds__(256) void embed_k(const int* __restrict__ x,
                                               const float* __restrict__ embed,
                                               unsigned short* __restrict__ xs){
    int wid  = (int)((blockIdx.x * blockDim.x + threadIdx.x) >> 6);
    int lane = threadIdx.x & 63;
    if (wid >= TB) return;
    int t = wid >> 7, b = wid & 127;
    int tok = x[b * TT + t];
    const float4* e = (const float4*)(embed + (size_t)tok * HH);
    float4 v0 = e[lane], v1 = e[lane + 64];
    float ss = v0.x*v0.x + v0.y*v0.y + v0.z*v0.z + v0.w*v0.w
             + v1.x*v1.x + v1.y*v1.y + v1.z*v1.z + v1.w*v1.w;
    #pragma unroll
    for (int off = 32; off > 0; off >>= 1) ss += __shfl_xor(ss, off, 64);
    float nrm = sqrtf(ss);
    float sc = (nrm > 1.f) ? 1.f / (nrm + 1e-7f) : 1.f;
    unsigned short* dst = xs + (size_t)wid * HH;
    ushort4 o0, o1;
    o0.x = f2bf(v0.x * sc); o0.y = f2bf(v0.y * sc); o0.z = f2bf(v0.z * sc); o0.w = f2bf(v0.w * sc);
    o1.x = f2bf(v1.x * sc); o1.y = f2bf(v1.y * sc); o1.z = f2bf(v1.z * sc); o1.w = f2bf(v1.w * sc);
    ((ushort4*)dst)[lane]      = o0;
    ((ushort4*)dst)[lane + 64] = o1;
}

// ---------------- bf16 GEMM (both dirs via blockIdx.z): C = A@W^T + bias ----------------
// m97 structure: 128x128 tile, BK=32, global_load_lds(16B) staging into linear
// LDS, 2-barrier K-loop, 4 waves each 64x64 (4x4 frags of 16x16x32 MFMA).
// Fragment/output mapping identical to the previously-verified direct version.
__global__ __launch_bounds__(256) void gemm2(const unsigned short* __restrict__ A0,
                                             const unsigned short* __restrict__ A1,
                                             const unsigned short* __restrict__ Wb_,
                                             const float* __restrict__ bias,
                                             unsigned short* __restrict__ Cout,
                                             int K, int CH){
    const int dz = blockIdx.z;
    const unsigned short* A  = dz ? A1 : A0;
    const unsigned short* W  = Wb_ + (size_t)dz * GG * K;
    const float*          bd = bias + dz * GG;
    unsigned short*       C  = Cout + (size_t)dz * CH * BB * GG;

    __shared__ __align__(16) unsigned short As[128 * 32];
    __shared__ __align__(16) unsigned short Bs[128 * 32];

    const int tid  = threadIdx.x;
    const int lane = tid & 63;
    const int wv   = tid >> 6;
    const int l15  = lane & 15, quad = lane >> 4;
    const int mw   = (wv >> 1) * 64;
    const int nw   = (wv & 1) * 64;
    const int m0   = blockIdx.x * 128;
    const int n0   = blockIdx.y * 128;

    // staging: chunk = 16 rows x 32 cols = 1KB; wave stages chunks 2wv, 2wv+1
    // lane l writes LDS chunkbase + l*16B  <->  row chunk*16 + (l>>2), col8 (l&3)
    const int srow = lane >> 2;
    const int scol = (lane & 3) * 8;
    const int c0 = wv * 2, c1 = wv * 2 + 1;
    const unsigned short* gA0 = A + (size_t)(m0 + c0 * 16 + srow) * K + scol;
    const unsigned short* gA1 = A + (size_t)(m0 + c1 * 16 + srow) * K + scol;
    const unsigned short* gB0 = W + (size_t)(n0 + c0 * 16 + srow) * K + scol;
    const unsigned short* gB1 = W + (size_t)(n0 + c1 * 16 + srow) * K + scol;

    f32x4 acc[4][4];
    #pragma unroll
    for (int i = 0; i < 4; i++)
        #pragma unroll
        for (int j = 0; j < 4; j++){ acc[i][j][0]=0.f; acc[i][j][1]=0.f; acc[i][j][2]=0.f; acc[i][j][3]=0.f; }

    for (int kk = 0; kk < K; kk += 32){
        __builtin_amdgcn_global_load_lds((const __attribute__((address_space(1))) void*)(gA0 + kk),
                                         (__attribute__((address_space(3))) void*)(As + c0 * 512), 16, 0, 0);
        __builtin_amdgcn_global_load_lds((const __attribute__((address_space(1))) void*)(gA1 + kk),
                                         (__attribute__((address_space(3))) void*)(As + c1 * 512), 16, 0, 0);
        __builtin_amdgcn_global_load_lds((const __attribute__((address_space(1))) void*)(gB0 + kk),
                                         (__attribute__((address_space(3))) void*)(Bs + c0 * 512), 16, 0, 0);
        __builtin_amdgcn_global_load_lds((const __attribute__((address_space(1))) void*)(gB1 + kk),
                                         (__attribute__((address_space(3))) void*)(Bs + c1 * 512), 16, 0, 0);
        __syncthreads();              // drains vmcnt -> staged data visible
        short8 a[4], b[4];
        #pragma unroll
        for (int i = 0; i < 4; i++) a[i] = *(const short8*)&As[(mw + i * 16 + l15) * 32 + quad * 8];
        #pragma unroll
        for (int j = 0; j < 4; j++) b[j] = *(const short8*)&Bs[(nw + j * 16 + l15) * 32 + quad * 8];
        #pragma unroll
        for (int i = 0; i < 4; i++)
            #pragma unroll
            for (int j = 0; j < 4; j++)
                acc[i][j] = __builtin_amdgcn_mfma_f32_16x16x32_bf16(a[i], b[j], acc[i][j], 0, 0, 0);
        __syncthreads();              // all reads done before next stage overwrites
    }

    #pragma unroll
    for (int i = 0; i < 4; i++){
        #pragma unroll
        for (int j = 0; j < 4; j++){
            int n = n0 + nw + j * 16 + l15;
            float bn = bd[n];
            #pragma unroll
            for (int r = 0; r < 4; r++){
                int m = m0 + mw + i * 16 + quad * 4 + r;
                C[(size_t)m * GG + n] = f2bf(acc[i][j][r] + bn);
            }
        }
    }
}

// ---------------- persistent BiLSTM recurrence v5 ----------------
// v4 structure preserved. New this round:
//  * preC gate slices prefetched into registers one step ahead (issued after
//    the flag store, so the HBM latency hides under the poll instead of
//    sitting exposed between MFMA and the gate math).
//  * sync flags padded to one 64B line per producer (previously 32 agent
//    stores/step landed in the same 2 cache lines).
__global__ __launch_bounds__(256) void lstm_seq(const unsigned short* __restrict__ preC, // [2][CH][128][2048]
                                                const unsigned short* __restrict__ whh,  // [2][2048][512]
                                                unsigned short* __restrict__ hA,         // blocked, 256KB
                                                unsigned short* __restrict__ hB,
                                                float* __restrict__ cstate,              // [2][128][512]
                                                unsigned short* __restrict__ hs_out,     // [TB][1024] (layer0)
                                                const float* __restrict__ cw,            // [9][1024] (layer1) or null
                                                float* __restrict__ em,                  // [T*B][9]  (layer1)
                                                int t0, int nsteps, int CH,
                                                unsigned int* __restrict__ bar){
    __shared__ unsigned short w_s[4][16][520];   // 66.6 KB
    __shared__ unsigned short hslab[64][520];    // 66.6 KB
    __shared__ unsigned short htile[64][20];     //  2.5 KB
    __shared__ float cw_s[NC][16];

    const int tid  = threadIdx.x;
    const int lane = tid & 63;
    const int wv   = tid >> 6;
    const int l15  = lane & 15, quad = lane >> 4;
    const int bx   = blockIdx.x;
    const int grp  = bx & 3;          // (d, mh)
    const int d    = grp >> 1;
    const int mh   = grp & 1;
    const int jc   = bx >> 2;         // 0..31
    const int m0   = mh * 64;

    // ---- stage W_hh slice into LDS (once) ----
    {
        const unsigned short* wbase = whh + (size_t)d * GG * HH;
        #pragma unroll
        for (int it = 0; it < 16; it++){
            int idx  = it * 256 + tid;
            int row  = idx >> 6;
            int col8 = idx & 63;
            int g2 = row >> 4, j2 = row & 15;
            short8 v = *(const short8*)(wbase + (size_t)(g2 * 512 + jc * 16 + j2) * HH + col8 * 8);
            *(short8*)&w_s[g2][j2][col8 * 8] = v;
        }
    }
    if (cw != nullptr && tid < NC * 16){
        int c = tid >> 4, j = tid & 15;
        cw_s[c][j] = cw[(size_t)c * 1024 + d * 512 + jc * 16 + j];
    }

    // ---- cstate -> 4 registers (held for the whole dispatch) ----
    float csreg[4];
    #pragma unroll
    for (int rr = 0; rr < 4; rr++){
        const int gm = m0 + wv * 16 + quad * 4 + rr;
        csreg[rr] = cstate[((size_t)d * BB + gm) * HH + jc * 16 + l15];
    }

    // ---- initial preC prefetch (step 0) ----
    unsigned short pf[4][4];
    {
        const int time0 = d ? (TT - 1 - t0) : t0;
        const int slot0 = time0 & (CH - 1);
        const unsigned short* p0 = preC + (((size_t)(d * CH + slot0)) * BB + (m0 + wv * 16 + quad * 4)) * GG + jc * 16 + l15;
        #pragma unroll
        for (int rr = 0; rr < 4; rr++)
            #pragma unroll
            for (int g = 0; g < 4; g++)
                pf[rr][g] = p0[(size_t)rr * GG + g * 512];
    }
    __syncthreads();

    const size_t slabElems = (size_t)32 * 64 * 16;   // per (d,mh): 32768 elems = 64 KB

    for (int ls = 0; ls < nsteps; ls++){
        const int tt   = t0 + ls;
        const unsigned short* srcB = (tt & 1) ? hB : hA;
        unsigned short*       dstB = (tt & 1) ? hA : hB;
        const unsigned long long* slab  = (const unsigned long long*)(srcB + (size_t)grp * slabElems);
        unsigned long long*       dtile = (unsigned long long*)(dstB + (size_t)grp * slabElems + (size_t)jc * 1024);

        // ---- consumer: contiguous 64KB slab -> LDS (coalesced 8B agent loads) ----
        #pragma unroll
        for (int it = 0; it < 32; it++){
            int n = it * 256 + tid;             // 8B units, 0..8191
            unsigned long long v = __hip_atomic_load(slab + n, __ATOMIC_RELAXED, __HIP_MEMORY_SCOPE_AGENT);
            int jcp = n >> 8;                   // source jc block
            int rem = n & 255;
            int row = rem >> 2;
            int c4  = (rem & 3) * 4;
            *(unsigned long long*)&hslab[row][jcp * 16 + c4] = v;
        }
        __syncthreads();

        // ---- MFMA: wave = m-subtile, 4 gate n-tiles, A & B from LDS ----
        f32x4 acc[4];
        #pragma unroll
        for (int g = 0; g < 4; g++){ acc[g][0]=0.f; acc[g][1]=0.f; acc[g][2]=0.f; acc[g][3]=0.f; }
        #pragma unroll
        for (int kk = 0; kk < 16; kk++){
            short8 a = *(const short8*)&hslab[wv * 16 + l15][kk * 32 + quad * 8];
            #pragma unroll
            for (int g = 0; g < 4; g++){
                short8 b = *(const short8*)&w_s[g][l15][kk * 32 + quad * 8];
                acc[g] = __builtin_amdgcn_mfma_f32_16x16x32_bf16(a, b, acc[g], 0, 0, 0);
            }
        }

        // ---- gate fusion: 4 cells/lane, cstate in regs, preC from prefetch regs ----
        #pragma unroll
        for (int rr = 0; rr < 4; rr++){
            const int lr = wv * 16 + quad * 4 + rr;
            const float zi = acc[0][rr] + bf2f(pf[rr][0]);
            const float zf = acc[1][rr] + bf2f(pf[rr][1]);
            const float zg = acc[2][rr] + bf2f(pf[rr][2]);
            const float zo = acc[3][rr] + bf2f(pf[rr][3]);
            float cs = sigm(zf) * csreg[rr] + sigm(zi) * tanh_f(zg);
            csreg[rr] = cs;
            htile[lr][l15] = f2bf(sigm(zo) * tanh_f(cs));
        }
        __syncthreads();

        // ---- producer: contiguous 2KB tile store (coalesced 8B agent stores) ----
        const int trow = tid >> 2, tc4 = (tid & 3) * 4;
        const unsigned long long hv8 = *(const unsigned long long*)&htile[trow][tc4];
        __hip_atomic_store(dtile + tid, hv8, __ATOMIC_RELAXED, __HIP_MEMORY_SCOPE_AGENT);

        __syncthreads();   // drains all threads' stores (vmcnt 0) before flag
        if (tid == 0)
            __hip_atomic_store(&bar[(grp * 32 + jc) * 16], (unsigned int)(ls + 1),
                               __ATOMIC_RELAXED, __HIP_MEMORY_SCOPE_AGENT);

        // ---- off-critical-path work (hidden under the poll) ----
        const int time = d ? (TT - 1 - tt) : tt;
        const bool more = (ls + 1 < nsteps);

        // next-step preC prefetch: issued here so HBM latency hides under poll
        unsigned short pfN[4][4];
        if (more){
            const int tt1 = tt + 1;
            const int time1 = d ? (TT - 1 - tt1) : tt1;
            const int slot1 = time1 & (CH - 1);
            const unsigned short* p1 = preC + (((size_t)(d * CH + slot1)) * BB + (m0 + wv * 16 + quad * 4)) * GG + jc * 16 + l15;
            #pragma unroll
            for (int rr = 0; rr < 4; rr++)
                #pragma unroll
                for (int g = 0; g < 4; g++)
                    pfN[rr][g] = p1[(size_t)rr * GG + g * 512];
        }

        if (cw == nullptr){
            *(unsigned long long*)(hs_out + ((size_t)time * BB + m0 + trow) * (2 * HH) + d * HH + jc * 16 + tc4) = hv8;
        } else {
            const int part = tid & 3;
            float hvv[4];
            #pragma unroll
            for (int k = 0; k < 4; k++) hvv[k] = bf2f(htile[trow][part * 4 + k]);
            float p[NC];
            #pragma unroll
            for (int c = 0; c < NC; c++){
                float s = 0.f;
                #pragma unroll
                for (int k = 0; k < 4; k++) s += hvv[k] * cw_s[c][part * 4 + k];
                p[c] = s;
            }
            #pragma unroll
            for (int c = 0; c < NC; c++){
                p[c] += __shfl_xor(p[c], 1, 64);
                p[c] += __shfl_xor(p[c], 2, 64);
            }
            if (part == 0){
                float* emr = em + ((size_t)time * BB + m0 + trow) * NC;
                #pragma unroll
                for (int c = 0; c < NC; c++) atomicAdd(emr + c, p[c]);
            }
        }

        // ---- poll the group's 32 flags ----
        if (more){
            if (tid < 32){
                const unsigned int tgt = (unsigned int)(ls + 1);
                const unsigned int* fl = bar + (grp * 32 + tid) * 16;
                while (__hip_atomic_load(fl, __ATOMIC_RELAXED, __HIP_MEMORY_SCOPE_AGENT) < tgt)
                    __builtin_amdgcn_s_sleep(1);
            }
            __syncthreads();
            __builtin_amdgcn_fence(__ATOMIC_ACQUIRE, "workgroup");  // compiler ordering only

            #pragma unroll
            for (int rr = 0; rr < 4; rr++)
                #pragma unroll
                for (int g = 0; g < 4; g++)
                    pf[rr][g] = pfN[rr][g];
        }
    }

    // ---- cstate regs -> global ----
    #pragma unroll
    for (int rr = 0; rr < 4; rr++){
        const int gm = m0 + wv * 16 + quad * 4 + rr;
        cstate[((size_t)d * BB + gm) * HH + jc * 16 + l15] = csreg[rr];
    }
}

// ---------------- em init: em[t,b,c] = cls_b[c] ----------------
__global__ void eminit(const float* __restrict__ cb, float* __restrict__ em){
    int i = blockIdx.x * blockDim.x + threadIdx.x;
    if (i < TB * NC) em[i] = cb[i % NC];
}

// ---------------- CRF per-sequence ----------------
__global__ __launch_bounds__(64) void crf_k(const int* __restrict__ y,
                                            const float* __restrict__ em,
                                            const float* __restrict__ cstart,
                                            const float* __restrict__ cend,
                                            const float* __restrict__ ctr,
                                            float* __restrict__ llh){
    int b = blockIdx.x;
    int lane = threadIdx.x;

    float sp = 0.f; int cnt = 0;
    for (int t = lane; t < TT; t += 64){
        int yt = y[b * TT + t];
        bool mk = (yt > -1);
        cnt += mk ? 1 : 0;
        if (t >= 1 && mk){
            int yp  = y[b * TT + t - 1];
            int tag  = yt > 0 ? yt : 0;
            int tagp = yp > 0 ? yp : 0;
            sp += ctr[tagp * NC + tag] + em[((size_t)t * BB + b) * NC + tag];
        }
    }
    #pragma unroll
    for (int off = 32; off > 0; off >>= 1){
        sp  += __shfl_xor(sp, off, 64);
        cnt += __shfl_xor(cnt, off, 64);
    }

    float trc[NC];
    #pragma unroll
    for (int cc2 = 0; cc2 < NC; cc2++) trc[cc2] = 0.f;
    if (lane < NC){
        #pragma unroll
        for (int cc2 = 0; cc2 < NC; cc2++) trc[cc2] = ctr[cc2 * NC + lane];
    }
    float alpha = -1e30f;
    if (lane < NC) alpha = cstart[lane] + em[(size_t)b * NC + lane];

    for (int t = 1; t < TT; t++){
        int yt = y[b * TT + t];
        bool mk = (yt > -1);
        float e = (lane < NC) ? em[((size_t)t * BB + b) * NC + lane] : 0.f;
        float v[NC]; float mx = -1e30f;
        #pragma unroll
        for (int cc2 = 0; cc2 < NC; cc2++){
            float ac = __shfl(alpha, cc2, 64);
            v[cc2] = ac + trc[cc2];
            mx = fmaxf(mx, v[cc2]);
        }
        float s = 0.f;
        #pragma unroll
        for (int cc2 = 0; cc2 < NC; cc2++) s += __expf(v[cc2] - mx);
        float nxt = mx + __logf(s) + e;
        if (mk && lane < NC) alpha = nxt;
    }

    float val = (lane < NC) ? (alpha + cend[lane]) : -1e30f;
    float mx = -1e30f;
    #pragma unroll
    for (int cc2 = 0; cc2 < NC; cc2++) mx = fmaxf(mx, __shfl(val, cc2, 64));
    float s = 0.f;
    #pragma unroll
    for (int cc2 = 0; cc2 < NC; cc2++) s += __expf(__shfl(val, cc2, 64) - mx);
    float denom = mx + __logf(s);

    if (lane == 0){
        int y0 = y[b * TT];
        int tag0 = y0 > 0 ? y0 : 0;
        int se = cnt - 1;
        if (se < 0) se = 0;
        int yl = y[b * TT + se];
        int tagl = yl > 0 ? yl : 0;
        float score = sp + cstart[tag0] + em[(size_t)b * NC + tag0] + cend[tagl];
        llh[b] = score - denom;
    }
}

__global__ void final_k(const float* __restrict__ llh, float* __restrict__ out){
    __shared__ float sm[128];
    int i = threadIdx.x;
    sm[i] = llh[i];
    __syncthreads();
    for (int s = 64; s > 0; s >>= 1){
        if (i < s) sm[i] += sm[i + s];
        __syncthreads();
    }
    if (i == 0) out[0] = -sm[0] / 128.f;
}

__global__ void sentinel_k(float* out, float v){ out[0] = v; }

extern "C" void kernel_launch(void* const* d_in, const int* in_sizes, int n_in,
                              void* d_out, int out_size, void* d_ws, size_t ws_size,
                              hipStream_t stream) {
    const int*   x     = (const int*)d_in[0];
    const int*   y     = (const int*)d_in[1];
    const float* embed = (const float*)d_in[2];
    const float* wih0  = (const float*)d_in[3];
    const float* whh0  = (const float*)d_in[4];
    const float* b0    = (const float*)d_in[5];
    const float* wih1  = (const float*)d_in[6];
    const float* whh1  = (const float*)d_in[7];
    const float* b1    = (const float*)d_in[8];
    const float* clsw  = (const float*)d_in[9];
    const float* clsb  = (const float*)d_in[10];
    const float* cst   = (const float*)d_in[11];
    const float* cen   = (const float*)d_in[12];
    const float* ctr   = (const float*)d_in[13];
    float* out = (float*)d_out;

    const size_t sz_w0   = (size_t)2 * GG * HH * 2;
    const size_t sz_w1   = (size_t)2 * GG * 1024 * 2;
    const size_t sz_xs   = (size_t)TB * HH * 2;
    const size_t sz_hs0  = (size_t)TB * 1024 * 2;
    const size_t sz_h    = (size_t)2 * BB * HH * 2;
    const size_t sz_c    = (size_t)2 * BB * HH * 4;
    const size_t sz_emis = (size_t)TB * NC * 4;
    const size_t sz_llh  = (size_t)BB * 4;
    const size_t sz_bar  = 8192;          // 4 grp x 32 jc x 64B line each
    auto rup = [](size_t v){ return (v + 255) & ~(size_t)255; };
    size_t fixed = rup(sz_w0) * 3 + rup(sz_w1) + rup(sz_xs) + rup(sz_hs0)
                 + rup(sz_h) * 2 + rup(sz_c) + rup(sz_emis) + rup(sz_llh) + rup(sz_bar);

    const int cands[7] = {256, 128, 64, 32, 16, 8, 4};
    int CH = 0;
    for (int i = 0; i < 7; i++){
        size_t need = fixed + rup((size_t)2 * cands[i] * BB * GG * 2);
        if (need <= ws_size){ CH = cands[i]; break; }
    }
    if (CH == 0){
        sentinel_k<<<1, 1, 0, stream>>>(out, -(float)(ws_size >> 20));
        return;
    }

    char* ws = (char*)d_ws;
    size_t off = 0;
    auto alloc = [&](size_t bytes) -> void* {
        void* p = (void*)(ws + off);
        off += (bytes + 255) & ~(size_t)255;
        return p;
    };
    unsigned short* wih0b = (unsigned short*)alloc(sz_w0);
    unsigned short* whh0b = (unsigned short*)alloc(sz_w0);
    unsigned short* whh1b = (unsigned short*)alloc(sz_w0);
    unsigned short* wih1b = (unsigned short*)alloc(sz_w1);
    unsigned short* xs    = (unsigned short*)alloc(sz_xs);
    unsigned short* hs0   = (unsigned short*)alloc(sz_hs0);
    unsigned short* hA    = (unsigned short*)alloc(sz_h);
    unsigned short* hB    = (unsigned short*)alloc(sz_h);
    float*          cbuf  = (float*)alloc(sz_c);
    float*          emis  = (float*)alloc(sz_emis);
    float*          llh   = (float*)alloc(sz_llh);
    unsigned int*   bar   = (unsigned int*)alloc(sz_bar);
    unsigned short* preC  = (unsigned short*)alloc((size_t)2 * CH * BB * GG * 2);

    castbf<<<(2 * GG * HH + 255) / 256, 256, 0, stream>>>(wih0, wih0b, 2 * GG * HH);
    castbf<<<(2 * GG * HH + 255) / 256, 256, 0, stream>>>(whh0, whh0b, 2 * GG * HH);
    castbf<<<(2 * GG * 1024 + 255) / 256, 256, 0, stream>>>(wih1, wih1b, 2 * GG * 1024);
    castbf<<<(2 * GG * HH + 255) / 256, 256, 0, stream>>>(whh1, whh1b, 2 * GG * HH);

    embed_k<<<TB / 4, 256, 0, stream>>>(x, embed, xs);

    const int nch = TT / CH;

    // ---------- layer 0 (writes hs0) ----------
    (void)hipMemsetAsync(hA, 0, sz_h, stream);
    (void)hipMemsetAsync(cbuf, 0, sz_c, stream);
    for (int c = 0; c < nch; c++){
        int t0f = c * CH;
        int t0b = TT - (c + 1) * CH;
        gemm2<<<dim3(CH, GG / 128, 2), 256, 0, stream>>>(
            xs + (size_t)t0f * BB * HH, xs + (size_t)t0b * BB * HH,
            wih0b, b0, preC, HH, CH);
        (void)hipMemsetAsync(bar, 0, sz_bar, stream);
        lstm_seq<<<128, 256, 0, stream>>>(preC, whh0b, hA, hB, cbuf, hs0,
                                          nullptr, emis, c * CH, CH, CH, bar);
    }

    // ---------- emissions init ----------
    eminit<<<(TB * NC + 255) / 256, 256, 0, stream>>>(clsb, emis);

    // ---------- layer 1 (fused emissions, no hs1) ----------
    (void)hipMemsetAsync(hA, 0, sz_h, stream);
    (void)hipMemsetAsync(cbuf, 0, sz_c, stream);
    for (int c = 0; c < nch; c++){
        int t0f = c * CH;
        int t0b = TT - (c + 1) * CH;
        gemm2<<<dim3(CH, GG / 128, 2), 256, 0, stream>>>(
            hs0 + (size_t)t0f * BB * 1024, hs0 + (size_t)t0b * BB * 1024,
            wih1b, b1, preC, 1024, CH);
        (void)hipMemsetAsync(bar, 0, sz_bar, stream);
        lstm_seq<<<128, 256, 0, stream>>>(preC, whh1b, hA, hB, cbuf, hs0,
                                          clsw, emis, c * CH, CH, CH, bar);
    }

    crf_k<<<BB, 64, 0, stream>>>(y, emis, cst, cen, ctr, llh);
    final_k<<<1, 128, 0, stream>>>(llh, out);
}

// Round 2
// 7972.530 us; speedup vs baseline: 1.1414x; 1.0069x over previous
//
#include <hip/hip_runtime.h>
#include <hip/hip_bf16.h>

#define VV 30000
#define HH 512
#define NC 9
#define BB 128
#define TT 256
#define GG 2048
#define TB (TT*BB)

using short8 = __attribute__((ext_vector_type(8))) short;
using f32x4  = __attribute__((ext_vector_type(4))) float;

__device__ inline float bf2f(unsigned short u){
    union { unsigned int i; float f; } v; v.i = ((unsigned int)u) << 16; return v.f;
}
__device__ inline unsigned short f2bf(float f){
    union { unsigned int i; float f; } v; v.f = f;
    unsigned int x = v.i;
    unsigned int r = (x + 0x7fffu + ((x >> 16) & 1u)) >> 16;
    return (unsigned short)r;
}
__device__ inline float sigm(float x){
    if (x >= 0.f){ return 1.f / (1.f + __expf(-x)); }
    float e = __expf(x); return e / (1.f + e);
}
__device__ inline float tanh_f(float x){
    float ax = fabsf(x);
    float e = __expf(-2.f * ax);
    float t = (1.f - e) / (1.f + e);
    return copysignf(t, x);
}

// ---------------- weight cast fp32 -> bf16 ----------------
__global__ void castbf(const float* __restrict__ in, unsigned short* __restrict__ out, int n){
    int i = blockIdx.x * blockDim.x + threadIdx.x;
    if (i < n) out[i] = f2bf(in[i]);
}

// ---------------- embedding + renorm -> xs bf16 [T*B][H] ----------------
__global__ __launch_bounds__(256) void embed_k(const int* __restrict__ x,
                                               const float* __restrict__ embed,
                                               unsigned short* __restrict__ xs){
    int wid  = (int)((blockIdx.x * blockDim.x + threadIdx.x) >> 6);
    int lane = threadIdx.x & 63;
    if (wid >= TB) return;
    int t = wid >> 7, b = wid & 127;
    int tok = x[b * TT + t];
    const float4* e = (const float4*)(embed + (size_t)tok * HH);
    float4 v0 = e[lane], v1 = e[lane + 64];
    float ss = v0.x*v0.x + v0.y*v0.y + v0.z*v0.z + v0.w*v0.w
             + v1.x*v1.x + v1.y*v1.y + v1.z*v1.z + v1.w*v1.w;
    #pragma unroll
    for (int off = 32; off > 0; off >>= 1) ss += __shfl_xor(ss, off, 64);
    float nrm = sqrtf(ss);
    float sc = (nrm > 1.f) ? 1.f / (nrm + 1e-7f) : 1.f;
    unsigned short* dst = xs + (size_t)wid * HH;
    ushort4 o0, o1;
    o0.x = f2bf(v0.x * sc); o0.y = f2bf(v0.y * sc); o0.z = f2bf(v0.z * sc); o0.w = f2bf(v0.w * sc);
    o1.x = f2bf(v1.x * sc); o1.y = f2bf(v1.y * sc); o1.z = f2bf(v1.z * sc); o1.w = f2bf(v1.w * sc);
    ((ushort4*)dst)[lane]      = o0;
    ((ushort4*)dst)[lane + 64] = o1;
}

// ---------------- bf16 GEMM (both dirs via blockIdx.z): C = A@W^T + bias ----------------
// v3: 128x128 tile, BK=32, DOUBLE-buffered global_load_lds with counted
// vmcnt(4) (T3 minimum-2-phase recipe) so prefetch stays in flight across the
// barrier; bijective XCD-chunk swizzle (m204) so each XCD keeps its B-panels
// L2-resident; epilogue bounced through (aliased) LDS for coalesced 16B stores.
__global__ __launch_bounds__(256) void gemm2(const unsigned short* __restrict__ A0,
                                             const unsigned short* __restrict__ A1,
                                             const unsigned short* __restrict__ Wb_,
                                             const float* __restrict__ bias,
                                             unsigned short* __restrict__ Cout,
                                             int K, int CH){
    const int dz = blockIdx.z;
    const unsigned short* A  = dz ? A1 : A0;
    const unsigned short* W  = Wb_ + (size_t)dz * GG * K;
    const float*          bd = bias + dz * GG;
    unsigned short*       C  = Cout + (size_t)dz * CH * BB * GG;

    // 32KB LDS: A0|A1|B0|B1 buffers of 8KB; whole thing aliased as C-stage.
    __shared__ __align__(16) unsigned short smem[16384];

    const int tid  = threadIdx.x;
    const int lane = tid & 63;
    const int wv   = tid >> 6;
    const int l15  = lane & 15, quad = lane >> 4;
    const int mw   = (wv >> 1) * 64;
    const int nw   = (wv & 1) * 64;

    // bijective XCD-chunk swizzle: id%8 -> contiguous chunk; x fastest within
    // chunk so each XCD sees a fixed pair of N-panels (B L2-resident).
    const int nwg   = gridDim.x * gridDim.y;           // % 8 == 0 for all CH
    const int chunk = nwg >> 3;
    const int id    = blockIdx.x + gridDim.x * blockIdx.y;
    const int nid   = (id & 7) * chunk + (id >> 3);
    const int m0    = (nid % gridDim.x) * 128;
    const int n0    = (nid / gridDim.x) * 128;

    // staging: chunk = 16 rows x 32 cols = 1KB; wave stages chunks 2wv, 2wv+1
    const int srow = lane >> 2;
    const int scol = (lane & 3) * 8;
    const int c0 = wv * 2, c1 = wv * 2 + 1;
    const unsigned short* gA0 = A + (size_t)(m0 + c0 * 16 + srow) * K + scol;
    const unsigned short* gA1 = A + (size_t)(m0 + c1 * 16 + srow) * K + scol;
    const unsigned short* gB0 = W + (size_t)(n0 + c0 * 16 + srow) * K + scol;
    const unsigned short* gB1 = W + (size_t)(n0 + c1 * 16 + srow) * K + scol;

    f32x4 acc[4][4];
    #pragma unroll
    for (int i = 0; i < 4; i++)
        #pragma unroll
        for (int j = 0; j < 4; j++){ acc[i][j][0]=0.f; acc[i][j][1]=0.f; acc[i][j][2]=0.f; acc[i][j][3]=0.f; }

    #define STAGE(bufi, kko)                                                                              \
        do {                                                                                              \
            __builtin_amdgcn_global_load_lds((const __attribute__((address_space(1))) void*)(gA0 + (kko)),\
                (__attribute__((address_space(3))) void*)(smem + (bufi) * 4096 + c0 * 512), 16, 0, 0);    \
            __builtin_amdgcn_global_load_lds((const __attribute__((address_space(1))) void*)(gA1 + (kko)),\
                (__attribute__((address_space(3))) void*)(smem + (bufi) * 4096 + c1 * 512), 16, 0, 0);    \
            __builtin_amdgcn_global_load_lds((const __attribute__((address_space(1))) void*)(gB0 + (kko)),\
                (__attribute__((address_space(3))) void*)(smem + 8192 + (bufi) * 4096 + c0 * 512), 16, 0, 0);\
            __builtin_amdgcn_global_load_lds((const __attribute__((address_space(1))) void*)(gB1 + (kko)),\
                (__attribute__((address_space(3))) void*)(smem + 8192 + (bufi) * 4096 + c1 * 512), 16, 0, 0);\
        } while (0)

    const int nk = K >> 5;
    STAGE(0, 0);                                  // prologue: tile 0 -> buf 0
    for (int t = 0; t < nk; ++t){
        const int buf = t & 1;
        const bool more = (t + 1 < nk);
        if (more){
            STAGE((t + 1) & 1, (t + 1) << 5);     // prefetch next tile
            __builtin_amdgcn_sched_barrier(0);
            asm volatile("s_waitcnt vmcnt(4)" ::: "memory");  // this tile landed; prefetch in flight
        } else {
            __builtin_amdgcn_sched_barrier(0);
            asm volatile("s_waitcnt vmcnt(0)" ::: "memory");
        }
        __builtin_amdgcn_s_barrier();             // all waves' stage for this tile done
        __builtin_amdgcn_sched_barrier(0);

        short8 a[4], b[4];
        #pragma unroll
        for (int i = 0; i < 4; i++) a[i] = *(const short8*)&smem[(size_t)buf * 4096 + (mw + i * 16 + l15) * 32 + quad * 8];
        #pragma unroll
        for (int j = 0; j < 4; j++) b[j] = *(const short8*)&smem[8192 + (size_t)buf * 4096 + (nw + j * 16 + l15) * 32 + quad * 8];
        #pragma unroll
        for (int i = 0; i < 4; i++)
            #pragma unroll
            for (int j = 0; j < 4; j++)
                acc[i][j] = __builtin_amdgcn_mfma_f32_16x16x32_bf16(a[i], b[j], acc[i][j], 0, 0, 0);

        __builtin_amdgcn_sched_barrier(0);
        __builtin_amdgcn_s_barrier();             // reads done -> next prefetch may overwrite
        __builtin_amdgcn_sched_barrier(0);
    }
    #undef STAGE

    // ---- epilogue: bias + bf16 into LDS C-stage (aliases A/B bufs), then coalesced 16B stores ----
    #pragma unroll
    for (int i = 0; i < 4; i++){
        #pragma unroll
        for (int j = 0; j < 4; j++){
            const int ncol = nw + j * 16 + l15;
            const float bn = bd[n0 + ncol];
            #pragma unroll
            for (int r = 0; r < 4; r++){
                const int mrow = mw + i * 16 + quad * 4 + r;
                smem[mrow * 128 + ncol] = f2bf(acc[i][j][r] + bn);
            }
        }
    }
    __syncthreads();
    #pragma unroll
    for (int it = 0; it < 8; it++){
        const int ch  = it * 256 + tid;           // 16B chunk index, 0..2047
        const int row = ch >> 4;
        const int col = (ch & 15) * 8;
        *(short8*)(C + (size_t)(m0 + row) * GG + n0 + col) = *(const short8*)&smem[row * 128 + col];
    }
}

// ---------------- persistent BiLSTM recurrence v5 ----------------
// v4 structure preserved. preC gate slices prefetched into registers one step
// ahead (HBM latency hides under the poll); sync flags padded to one 64B line
// per producer.
__global__ __launch_bounds__(256) void lstm_seq(const unsigned short* __restrict__ preC, // [2][CH][128][2048]
                                                const unsigned short* __restrict__ whh,  // [2][2048][512]
                                                unsigned short* __restrict__ hA,         // blocked, 256KB
                                                unsigned short* __restrict__ hB,
                                                float* __restrict__ cstate,              // [2][128][512]
                                                unsigned short* __restrict__ hs_out,     // [TB][1024] (layer0)
                                                const float* __restrict__ cw,            // [9][1024] (layer1) or null
                                                float* __restrict__ em,                  // [T*B][9]  (layer1)
                                                int t0, int nsteps, int CH,
                                                unsigned int* __restrict__ bar){
    __shared__ unsigned short w_s[4][16][520];   // 66.6 KB
    __shared__ unsigned short hslab[64][520];    // 66.6 KB
    __shared__ unsigned short htile[64][20];     //  2.5 KB
    __shared__ float cw_s[NC][16];

    const int tid  = threadIdx.x;
    const int lane = tid & 63;
    const int wv   = tid >> 6;
    const int l15  = lane & 15, quad = lane >> 4;
    const int bx   = blockIdx.x;
    const int grp  = bx & 3;          // (d, mh)
    const int d    = grp >> 1;
    const int mh   = grp & 1;
    const int jc   = bx >> 2;         // 0..31
    const int m0   = mh * 64;

    // ---- stage W_hh slice into LDS (once) ----
    {
        const unsigned short* wbase = whh + (size_t)d * GG * HH;
        #pragma unroll
        for (int it = 0; it < 16; it++){
            int idx  = it * 256 + tid;
            int row  = idx >> 6;
            int col8 = idx & 63;
            int g2 = row >> 4, j2 = row & 15;
            short8 v = *(const short8*)(wbase + (size_t)(g2 * 512 + jc * 16 + j2) * HH + col8 * 8);
            *(short8*)&w_s[g2][j2][col8 * 8] = v;
        }
    }
    if (cw != nullptr && tid < NC * 16){
        int c = tid >> 4, j = tid & 15;
        cw_s[c][j] = cw[(size_t)c * 1024 + d * 512 + jc * 16 + j];
    }

    // ---- cstate -> 4 registers (held for the whole dispatch) ----
    float csreg[4];
    #pragma unroll
    for (int rr = 0; rr < 4; rr++){
        const int gm = m0 + wv * 16 + quad * 4 + rr;
        csreg[rr] = cstate[((size_t)d * BB + gm) * HH + jc * 16 + l15];
    }

    // ---- initial preC prefetch (step 0) ----
    unsigned short pf[4][4];
    {
        const int time0 = d ? (TT - 1 - t0) : t0;
        const int slot0 = time0 & (CH - 1);
        const unsigned short* p0 = preC + (((size_t)(d * CH + slot0)) * BB + (m0 + wv * 16 + quad * 4)) * GG + jc * 16 + l15;
        #pragma unroll
        for (int rr = 0; rr < 4; rr++)
            #pragma unroll
            for (int g = 0; g < 4; g++)
                pf[rr][g] = p0[(size_t)rr * GG + g * 512];
    }
    __syncthreads();

    const size_t slabElems = (size_t)32 * 64 * 16;   // per (d,mh): 32768 elems = 64 KB

    for (int ls = 0; ls < nsteps; ls++){
        const int tt   = t0 + ls;
        const unsigned short* srcB = (tt & 1) ? hB : hA;
        unsigned short*       dstB = (tt & 1) ? hA : hB;
        const unsigned long long* slab  = (const unsigned long long*)(srcB + (size_t)grp * slabElems);
        unsigned long long*       dtile = (unsigned long long*)(dstB + (size_t)grp * slabElems + (size_t)jc * 1024);

        // ---- consumer: contiguous 64KB slab -> LDS (coalesced 8B agent loads) ----
        #pragma unroll
        for (int it = 0; it < 32; it++){
            int n = it * 256 + tid;             // 8B units, 0..8191
            unsigned long long v = __hip_atomic_load(slab + n, __ATOMIC_RELAXED, __HIP_MEMORY_SCOPE_AGENT);
            int jcp = n >> 8;                   // source jc block
            int rem = n & 255;
            int row = rem >> 2;
            int c4  = (rem & 3) * 4;
            *(unsigned long long*)&hslab[row][jcp * 16 + c4] = v;
        }
        __syncthreads();

        // ---- MFMA: wave = m-subtile, 4 gate n-tiles, A & B from LDS ----
        f32x4 acc[4];
        #pragma unroll
        for (int g = 0; g < 4; g++){ acc[g][0]=0.f; acc[g][1]=0.f; acc[g][2]=0.f; acc[g][3]=0.f; }
        #pragma unroll
        for (int kk = 0; kk < 16; kk++){
            short8 a = *(const short8*)&hslab[wv * 16 + l15][kk * 32 + quad * 8];
            #pragma unroll
            for (int g = 0; g < 4; g++){
                short8 b = *(const short8*)&w_s[g][l15][kk * 32 + quad * 8];
                acc[g] = __builtin_amdgcn_mfma_f32_16x16x32_bf16(a, b, acc[g], 0, 0, 0);
            }
        }

        // ---- gate fusion: 4 cells/lane, cstate in regs, preC from prefetch regs ----
        #pragma unroll
        for (int rr = 0; rr < 4; rr++){
            const int lr = wv * 16 + quad * 4 + rr;
            const float zi = acc[0][rr] + bf2f(pf[rr][0]);
            const float zf = acc[1][rr] + bf2f(pf[rr][1]);
            const float zg = acc[2][rr] + bf2f(pf[rr][2]);
            const float zo = acc[3][rr] + bf2f(pf[rr][3]);
            float cs = sigm(zf) * csreg[rr] + sigm(zi) * tanh_f(zg);
            csreg[rr] = cs;
            htile[lr][l15] = f2bf(sigm(zo) * tanh_f(cs));
        }
        __syncthreads();

        // ---- producer: contiguous 2KB tile store (coalesced 8B agent stores) ----
        const int trow = tid >> 2, tc4 = (tid & 3) * 4;
        const unsigned long long hv8 = *(const unsigned long long*)&htile[trow][tc4];
        __hip_atomic_store(dtile + tid, hv8, __ATOMIC_RELAXED, __HIP_MEMORY_SCOPE_AGENT);

        __syncthreads();   // drains all threads' stores (vmcnt 0) before flag
        if (tid == 0)
            __hip_atomic_store(&bar[(grp * 32 + jc) * 16], (unsigned int)(ls + 1),
                               __ATOMIC_RELAXED, __HIP_MEMORY_SCOPE_AGENT);

        // ---- off-critical-path work (hidden under the poll) ----
        const int time = d ? (TT - 1 - tt) : tt;
        const bool more = (ls + 1 < nsteps);

        // next-step preC prefetch: issued here so HBM latency hides under poll
        unsigned short pfN[4][4];
        if (more){
            const int tt1 = tt + 1;
            const int time1 = d ? (TT - 1 - tt1) : tt1;
            const int slot1 = time1 & (CH - 1);
            const unsigned short* p1 = preC + (((size_t)(d * CH + slot1)) * BB + (m0 + wv * 16 + quad * 4)) * GG + jc * 16 + l15;
            #pragma unroll
            for (int rr = 0; rr < 4; rr++)
                #pragma unroll
                for (int g = 0; g < 4; g++)
                    pfN[rr][g] = p1[(size_t)rr * GG + g * 512];
        }

        if (cw == nullptr){
            *(unsigned long long*)(hs_out + ((size_t)time * BB + m0 + trow) * (2 * HH) + d * HH + jc * 16 + tc4) = hv8;
        } else {
            const int part = tid & 3;
            float hvv[4];
            #pragma unroll
            for (int k = 0; k < 4; k++) hvv[k] = bf2f(htile[trow][part * 4 + k]);
            float p[NC];
            #pragma unroll
            for (int c = 0; c < NC; c++){
                float s = 0.f;
                #pragma unroll
                for (int k = 0; k < 4; k++) s += hvv[k] * cw_s[c][part * 4 + k];
                p[c] = s;
            }
            #pragma unroll
            for (int c = 0; c < NC; c++){
                p[c] += __shfl_xor(p[c], 1, 64);
                p[c] += __shfl_xor(p[c], 2, 64);
            }
            if (part == 0){
                float* emr = em + ((size_t)time * BB + m0 + trow) * NC;
                #pragma unroll
                for (int c = 0; c < NC; c++) atomicAdd(emr + c, p[c]);
            }
        }

        // ---- poll the group's 32 flags ----
        if (more){
            if (tid < 32){
                const unsigned int tgt = (unsigned int)(ls + 1);
                const unsigned int* fl = bar + (grp * 32 + tid) * 16;
                while (__hip_atomic_load(fl, __ATOMIC_RELAXED, __HIP_MEMORY_SCOPE_AGENT) < tgt)
                    __builtin_amdgcn_s_sleep(1);
            }
            __syncthreads();
            __builtin_amdgcn_fence(__ATOMIC_ACQUIRE, "workgroup");  // compiler ordering only

            #pragma unroll
            for (int rr = 0; rr < 4; rr++)
                #pragma unroll
                for (int g = 0; g < 4; g++)
                    pf[rr][g] = pfN[rr][g];
        }
    }

    // ---- cstate regs -> global ----
    #pragma unroll
    for (int rr = 0; rr < 4; rr++){
        const int gm = m0 + wv * 16 + quad * 4 + rr;
        cstate[((size_t)d * BB + gm) * HH + jc * 16 + l15] = csreg[rr];
    }
}

// ---------------- em init: em[t,b,c] = cls_b[c] ----------------
__global__ void eminit(const float* __restrict__ cb, float* __restrict__ em){
    int i = blockIdx.x * blockDim.x + threadIdx.x;
    if (i < TB * NC) em[i] = cb[i % NC];
}

// ---------------- CRF per-sequence ----------------
__global__ __launch_bounds__(64) void crf_k(const int* __restrict__ y,
                                            const float* __restrict__ em,
                                            const float* __restrict__ cstart,
                                            const float* __restrict__ cend,
                                            const float* __restrict__ ctr,
                                            float* __restrict__ llh){
    int b = blockIdx.x;
    int lane = threadIdx.x;

    float sp = 0.f; int cnt = 0;
    for (int t = lane; t < TT; t += 64){
        int yt = y[b * TT + t];
        bool mk = (yt > -1);
        cnt += mk ? 1 : 0;
        if (t >= 1 && mk){
            int yp  = y[b * TT + t - 1];
            int tag  = yt > 0 ? yt : 0;
            int tagp = yp > 0 ? yp : 0;
            sp += ctr[tagp * NC + tag] + em[((size_t)t * BB + b) * NC + tag];
        }
    }
    #pragma unroll
    for (int off = 32; off > 0; off >>= 1){
        sp  += __shfl_xor(sp, off, 64);
        cnt += __shfl_xor(cnt, off, 64);
    }

    float trc[NC];
    #pragma unroll
    for (int cc2 = 0; cc2 < NC; cc2++) trc[cc2] = 0.f;
    if (lane < NC){
        #pragma unroll
        for (int cc2 = 0; cc2 < NC; cc2++) trc[cc2] = ctr[cc2 * NC + lane];
    }
    float alpha = -1e30f;
    if (lane < NC) alpha = cstart[lane] + em[(size_t)b * NC + lane];

    for (int t = 1; t < TT; t++){
        int yt = y[b * TT + t];
        bool mk = (yt > -1);
        float e = (lane < NC) ? em[((size_t)t * BB + b) * NC + lane] : 0.f;
        float v[NC]; float mx = -1e30f;
        #pragma unroll
        for (int cc2 = 0; cc2 < NC; cc2++){
            float ac = __shfl(alpha, cc2, 64);
            v[cc2] = ac + trc[cc2];
            mx = fmaxf(mx, v[cc2]);
        }
        float s = 0.f;
        #pragma unroll
        for (int cc2 = 0; cc2 < NC; cc2++) s += __expf(v[cc2] - mx);
        float nxt = mx + __logf(s) + e;
        if (mk && lane < NC) alpha = nxt;
    }

    float val = (lane < NC) ? (alpha + cend[lane]) : -1e30f;
    float mx = -1e30f;
    #pragma unroll
    for (int cc2 = 0; cc2 < NC; cc2++) mx = fmaxf(mx, __shfl(val, cc2, 64));
    float s = 0.f;
    #pragma unroll
    for (int cc2 = 0; cc2 < NC; cc2++) s += __expf(__shfl(val, cc2, 64) - mx);
    float denom = mx + __logf(s);

    if (lane == 0){
        int y0 = y[b * TT];
        int tag0 = y0 > 0 ? y0 : 0;
        int se = cnt - 1;
        if (se < 0) se = 0;
        int yl = y[b * TT + se];
        int tagl = yl > 0 ? yl : 0;
        float score = sp + cstart[tag0] + em[(size_t)b * NC + tag0] + cend[tagl];
        llh[b] = score - denom;
    }
}

__global__ void final_k(const float* __restrict__ llh, float* __restrict__ out){
    __shared__ float sm[128];
    int i = threadIdx.x;
    sm[i] = llh[i];
    __syncthreads();
    for (int s = 64; s > 0; s >>= 1){
        if (i < s) sm[i] += sm[i + s];
        __syncthreads();
    }
    if (i == 0) out[0] = -sm[0] / 128.f;
}

__global__ void sentinel_k(float* out, float v){ out[0] = v; }

extern "C" void kernel_launch(void* const* d_in, const int* in_sizes, int n_in,
                              void* d_out, int out_size, void* d_ws, size_t ws_size,
                              hipStream_t stream) {
    const int*   x     = (const int*)d_in[0];
    const int*   y     = (const int*)d_in[1];
    const float* embed = (const float*)d_in[2];
    const float* wih0  = (const float*)d_in[3];
    const float* whh0  = (const float*)d_in[4];
    const float* b0    = (const float*)d_in[5];
    const float* wih1  = (const float*)d_in[6];
    const float* whh1  = (const float*)d_in[7];
    const float* b1    = (const float*)d_in[8];
    const float* clsw  = (const float*)d_in[9];
    const float* clsb  = (const float*)d_in[10];
    const float* cst   = (const float*)d_in[11];
    const float* cen   = (const float*)d_in[12];
    const float* ctr   = (const float*)d_in[13];
    float* out = (float*)d_out;

    const size_t sz_w0   = (size_t)2 * GG * HH * 2;
    const size_t sz_w1   = (size_t)2 * GG * 1024 * 2;
    const size_t sz_xs   = (size_t)TB * HH * 2;
    const size_t sz_hs0  = (size_t)TB * 1024 * 2;
    const size_t sz_h    = (size_t)2 * BB * HH * 2;
    const size_t sz_c    = (size_t)2 * BB * HH * 4;
    const size_t sz_emis = (size_t)TB * NC * 4;
    const size_t sz_llh  = (size_t)BB * 4;
    const size_t sz_bar  = 8192;          // 4 grp x 32 jc x 64B line each
    auto rup = [](size_t v){ return (v + 255) & ~(size_t)255; };
    size_t fixed = rup(sz_w0) * 3 + rup(sz_w1) + rup(sz_xs) + rup(sz_hs0)
                 + rup(sz_h) * 2 + rup(sz_c) + rup(sz_emis) + rup(sz_llh) + rup(sz_bar);

    const int cands[7] = {256, 128, 64, 32, 16, 8, 4};
    int CH = 0;
    for (int i = 0; i < 7; i++){
        size_t need = fixed + rup((size_t)2 * cands[i] * BB * GG * 2);
        if (need <= ws_size){ CH = cands[i]; break; }
    }
    if (CH == 0){
        sentinel_k<<<1, 1, 0, stream>>>(out, -(float)(ws_size >> 20));
        return;
    }

    char* ws = (char*)d_ws;
    size_t off = 0;
    auto alloc = [&](size_t bytes) -> void* {
        void* p = (void*)(ws + off);
        off += (bytes + 255) & ~(size_t)255;
        return p;
    };
    unsigned short* wih0b = (unsigned short*)alloc(sz_w0);
    unsigned short* whh0b = (unsigned short*)alloc(sz_w0);
    unsigned short* whh1b = (unsigned short*)alloc(sz_w0);
    unsigned short* wih1b = (unsigned short*)alloc(sz_w1);
    unsigned short* xs    = (unsigned short*)alloc(sz_xs);
    unsigned short* hs0   = (unsigned short*)alloc(sz_hs0);
    unsigned short* hA    = (unsigned short*)alloc(sz_h);
    unsigned short* hB    = (unsigned short*)alloc(sz_h);
    float*          cbuf  = (float*)alloc(sz_c);
    float*          emis  = (float*)alloc(sz_emis);
    float*          llh   = (float*)alloc(sz_llh);
    unsigned int*   bar   = (unsigned int*)alloc(sz_bar);
    unsigned short* preC  = (unsigned short*)alloc((size_t)2 * CH * BB * GG * 2);

    castbf<<<(2 * GG * HH + 255) / 256, 256, 0, stream>>>(wih0, wih0b, 2 * GG * HH);
    castbf<<<(2 * GG * HH + 255) / 256, 256, 0, stream>>>(whh0, whh0b, 2 * GG * HH);
    castbf<<<(2 * GG * 1024 + 255) / 256, 256, 0, stream>>>(wih1, wih1b, 2 * GG * 1024);
    castbf<<<(2 * GG * HH + 255) / 256, 256, 0, stream>>>(whh1, whh1b, 2 * GG * HH);

    embed_k<<<TB / 4, 256, 0, stream>>>(x, embed, xs);

    const int nch = TT / CH;

    // ---------- layer 0 (writes hs0) ----------
    (void)hipMemsetAsync(hA, 0, sz_h, stream);
    (void)hipMemsetAsync(cbuf, 0, sz_c, stream);
    for (int c = 0; c < nch; c++){
        int t0f = c * CH;
        int t0b = TT - (c + 1) * CH;
        gemm2<<<dim3(CH, GG / 128, 2), 256, 0, stream>>>(
            xs + (size_t)t0f * BB * HH, xs + (size_t)t0b * BB * HH,
            wih0b, b0, preC, HH, CH);
        (void)hipMemsetAsync(bar, 0, sz_bar, stream);
        lstm_seq<<<128, 256, 0, stream>>>(preC, whh0b, hA, hB, cbuf, hs0,
                                          nullptr, emis, c * CH, CH, CH, bar);
    }

    // ---------- emissions init ----------
    eminit<<<(TB * NC + 255) / 256, 256, 0, stream>>>(clsb, emis);

    // ---------- layer 1 (fused emissions, no hs1) ----------
    (void)hipMemsetAsync(hA, 0, sz_h, stream);
    (void)hipMemsetAsync(cbuf, 0, sz_c, stream);
    for (int c = 0; c < nch; c++){
        int t0f = c * CH;
        int t0b = TT - (c + 1) * CH;
        gemm2<<<dim3(CH, GG / 128, 2), 256, 0, stream>>>(
            hs0 + (size_t)t0f * BB * 1024, hs0 + (size_t)t0b * BB * 1024,
            wih1b, b1, preC, 1024, CH);
        (void)hipMemsetAsync(bar, 0, sz_bar, stream);
        lstm_seq<<<128, 256, 0, stream>>>(preC, whh1b, hA, hB, cbuf, hs0,
                                          clsw, emis, c * CH, CH, CH, bar);
    }

    crf_k<<<BB, 64, 0, stream>>>(y, emis, cst, cen, ctr, llh);
    final_k<<<1, 128, 0, stream>>>(llh, out);
}

// Round 3
// 5014.744 us; speedup vs baseline: 1.8147x; 1.5898x over previous
//
#include <hip/hip_runtime.h>
#include <hip/hip_bf16.h>

#define VV 30000
#define HH 512
#define NC 9
#define BB 128
#define TT 256
#define GG 2048
#define TB (TT*BB)

using short8 = __attribute__((ext_vector_type(8))) short;
using f32x4  = __attribute__((ext_vector_type(4))) float;

__device__ inline float bf2f(unsigned short u){
    union { unsigned int i; float f; } v; v.i = ((unsigned int)u) << 16; return v.f;
}
__device__ inline unsigned short f2bf(float f){
    union { unsigned int i; float f; } v; v.f = f;
    unsigned int x = v.i;
    unsigned int r = (x + 0x7fffu + ((x >> 16) & 1u)) >> 16;
    return (unsigned short)r;
}
__device__ inline float sigm(float x){
    if (x >= 0.f){ return 1.f / (1.f + __expf(-x)); }
    float e = __expf(x); return e / (1.f + e);
}
__device__ inline float tanh_f(float x){
    float ax = fabsf(x);
    float e = __expf(-2.f * ax);
    float t = (1.f - e) / (1.f + e);
    return copysignf(t, x);
}

// ---------------- weight cast fp32 -> bf16 ----------------
__global__ void castbf(const float* __restrict__ in, unsigned short* __restrict__ out, int n){
    int i = blockIdx.x * blockDim.x + threadIdx.x;
    if (i < n) out[i] = f2bf(in[i]);
}

// ---------------- embedding + renorm -> xs bf16 [T*B][H] ----------------
__global__ __launch_bounds__(256) void embed_k(const int* __restrict__ x,
                                               const float* __restrict__ embed,
                                               unsigned short* __restrict__ xs){
    int wid  = (int)((blockIdx.x * blockDim.x + threadIdx.x) >> 6);
    int lane = threadIdx.x & 63;
    if (wid >= TB) return;
    int t = wid >> 7, b = wid & 127;
    int tok = x[b * TT + t];
    const float4* e = (const float4*)(embed + (size_t)tok * HH);
    float4 v0 = e[lane], v1 = e[lane + 64];
    float ss = v0.x*v0.x + v0.y*v0.y + v0.z*v0.z + v0.w*v0.w
             + v1.x*v1.x + v1.y*v1.y + v1.z*v1.z + v1.w*v1.w;
    #pragma unroll
    for (int off = 32; off > 0; off >>= 1) ss += __shfl_xor(ss, off, 64);
    float nrm = sqrtf(ss);
    float sc = (nrm > 1.f) ? 1.f / (nrm + 1e-7f) : 1.f;
    unsigned short* dst = xs + (size_t)wid * HH;
    ushort4 o0, o1;
    o0.x = f2bf(v0.x * sc); o0.y = f2bf(v0.y * sc); o0.z = f2bf(v0.z * sc); o0.w = f2bf(v0.w * sc);
    o1.x = f2bf(v1.x * sc); o1.y = f2bf(v1.y * sc); o1.z = f2bf(v1.z * sc); o1.w = f2bf(v1.w * sc);
    ((ushort4*)dst)[lane]      = o0;
    ((ushort4*)dst)[lane + 64] = o1;
}

// ---------------- bf16 GEMM (both dirs via blockIdx.z): C = A@W^T + bias ----------------
// 128x128 tile, BK=32, double-buffered global_load_lds with counted vmcnt(4);
// bijective XCD-chunk swizzle; epilogue bounced through LDS for 16B stores.
__global__ __launch_bounds__(256) void gemm2(const unsigned short* __restrict__ A0,
                                             const unsigned short* __restrict__ A1,
                                             const unsigned short* __restrict__ Wb_,
                                             const float* __restrict__ bias,
                                             unsigned short* __restrict__ Cout,
                                             int K, int CH){
    const int dz = blockIdx.z;
    const unsigned short* A  = dz ? A1 : A0;
    const unsigned short* W  = Wb_ + (size_t)dz * GG * K;
    const float*          bd = bias + dz * GG;
    unsigned short*       C  = Cout + (size_t)dz * CH * BB * GG;

    __shared__ __align__(16) unsigned short smem[16384];

    const int tid  = threadIdx.x;
    const int lane = tid & 63;
    const int wv   = tid >> 6;
    const int l15  = lane & 15, quad = lane >> 4;
    const int mw   = (wv >> 1) * 64;
    const int nw   = (wv & 1) * 64;

    const int nwg   = gridDim.x * gridDim.y;
    const int chunk = nwg >> 3;
    const int id    = blockIdx.x + gridDim.x * blockIdx.y;
    const int nid   = (id & 7) * chunk + (id >> 3);
    const int m0    = (nid % gridDim.x) * 128;
    const int n0    = (nid / gridDim.x) * 128;

    const int srow = lane >> 2;
    const int scol = (lane & 3) * 8;
    const int c0 = wv * 2, c1 = wv * 2 + 1;
    const unsigned short* gA0 = A + (size_t)(m0 + c0 * 16 + srow) * K + scol;
    const unsigned short* gA1 = A + (size_t)(m0 + c1 * 16 + srow) * K + scol;
    const unsigned short* gB0 = W + (size_t)(n0 + c0 * 16 + srow) * K + scol;
    const unsigned short* gB1 = W + (size_t)(n0 + c1 * 16 + srow) * K + scol;

    f32x4 acc[4][4];
    #pragma unroll
    for (int i = 0; i < 4; i++)
        #pragma unroll
        for (int j = 0; j < 4; j++){ acc[i][j][0]=0.f; acc[i][j][1]=0.f; acc[i][j][2]=0.f; acc[i][j][3]=0.f; }

    #define STAGE(bufi, kko)                                                                              \
        do {                                                                                              \
            __builtin_amdgcn_global_load_lds((const __attribute__((address_space(1))) void*)(gA0 + (kko)),\
                (__attribute__((address_space(3))) void*)(smem + (bufi) * 4096 + c0 * 512), 16, 0, 0);    \
            __builtin_amdgcn_global_load_lds((const __attribute__((address_space(1))) void*)(gA1 + (kko)),\
                (__attribute__((address_space(3))) void*)(smem + (bufi) * 4096 + c1 * 512), 16, 0, 0);    \
            __builtin_amdgcn_global_load_lds((const __attribute__((address_space(1))) void*)(gB0 + (kko)),\
                (__attribute__((address_space(3))) void*)(smem + 8192 + (bufi) * 4096 + c0 * 512), 16, 0, 0);\
            __builtin_amdgcn_global_load_lds((const __attribute__((address_space(1))) void*)(gB1 + (kko)),\
                (__attribute__((address_space(3))) void*)(smem + 8192 + (bufi) * 4096 + c1 * 512), 16, 0, 0);\
        } while (0)

    const int nk = K >> 5;
    STAGE(0, 0);
    for (int t = 0; t < nk; ++t){
        const int buf = t & 1;
        const bool more = (t + 1 < nk);
        if (more){
            STAGE((t + 1) & 1, (t + 1) << 5);
            __builtin_amdgcn_sched_barrier(0);
            asm volatile("s_waitcnt vmcnt(4)" ::: "memory");
        } else {
            __builtin_amdgcn_sched_barrier(0);
            asm volatile("s_waitcnt vmcnt(0)" ::: "memory");
        }
        __builtin_amdgcn_s_barrier();
        __builtin_amdgcn_sched_barrier(0);

        short8 a[4], b[4];
        #pragma unroll
        for (int i = 0; i < 4; i++) a[i] = *(const short8*)&smem[(size_t)buf * 4096 + (mw + i * 16 + l15) * 32 + quad * 8];
        #pragma unroll
        for (int j = 0; j < 4; j++) b[j] = *(const short8*)&smem[8192 + (size_t)buf * 4096 + (nw + j * 16 + l15) * 32 + quad * 8];
        #pragma unroll
        for (int i = 0; i < 4; i++)
            #pragma unroll
            for (int j = 0; j < 4; j++)
                acc[i][j] = __builtin_amdgcn_mfma_f32_16x16x32_bf16(a[i], b[j], acc[i][j], 0, 0, 0);

        __builtin_amdgcn_sched_barrier(0);
        __builtin_amdgcn_s_barrier();
        __builtin_amdgcn_sched_barrier(0);
    }
    #undef STAGE

    #pragma unroll
    for (int i = 0; i < 4; i++){
        #pragma unroll
        for (int j = 0; j < 4; j++){
            const int ncol = nw + j * 16 + l15;
            const float bn = bd[n0 + ncol];
            #pragma unroll
            for (int r = 0; r < 4; r++){
                const int mrow = mw + i * 16 + quad * 4 + r;
                smem[mrow * 128 + ncol] = f2bf(acc[i][j][r] + bn);
            }
        }
    }
    __syncthreads();
    #pragma unroll
    for (int it = 0; it < 8; it++){
        const int ch  = it * 256 + tid;
        const int row = ch >> 4;
        const int col = (ch & 15) * 8;
        *(short8*)(C + (size_t)(m0 + row) * GG + n0 + col) = *(const short8*)&smem[row * 128 + col];
    }
}

// ---------------- persistent BiLSTM recurrence v6: per-WAVE rings ----------------
// Dependency decomposition: wave wv of block (grp,jc) produces h rows
// [wv*16, wv*16+16) x 16 cols and consumes ONLY those rows from all 32 jc
// producers of the SAME wv. So the block-level all-gather becomes 4
// independent 32-wave rings:
//  * per-wave flags bar[grp][wv][jc] (64B-padded); release = own vmcnt(0)
//  * consumers load MFMA A-fragments directly global->regs (32x8B agent
//    loads; hslab LDS bounce removed -- each element was read exactly once)
//  * ZERO __syncthreads in the step loop; waves free-run. Cross-wv waves
//    share nothing (disjoint rows/LDS quadrants/flags); within a ring the
//    flag poll bounds skew to 1 step, so the 2-deep h buffer is race-free
//    by the same argument as the block-level version.
__global__ __launch_bounds__(256) void lstm_seq(const unsigned short* __restrict__ preC, // [2][CH][128][2048]
                                                const unsigned short* __restrict__ whh,  // [2][2048][512]
                                                unsigned short* __restrict__ hA,         // blocked, 256KB
                                                unsigned short* __restrict__ hB,
                                                float* __restrict__ cstate,              // [2][128][512]
                                                unsigned short* __restrict__ hs_out,     // [TB][1024] (layer0)
                                                const float* __restrict__ cw,            // [9][1024] (layer1) or null
                                                float* __restrict__ em,                  // [T*B][9]  (layer1)
                                                int t0, int nsteps, int CH,
                                                unsigned int* __restrict__ bar){
    __shared__ unsigned short w_s[4][16][520];   // 66.6 KB (read-only after init)
    __shared__ unsigned short htile[64][20];     //  2.5 KB (per-wave disjoint quadrants)
    __shared__ float cw_s[NC][16];

    const int tid  = threadIdx.x;
    const int lane = tid & 63;
    const int wv   = tid >> 6;
    const int l15  = lane & 15, quad = lane >> 4;
    const int bx   = blockIdx.x;
    const int grp  = bx & 3;          // (d, mh)
    const int d    = grp >> 1;
    const int mh   = grp & 1;
    const int jc   = bx >> 2;         // 0..31
    const int m0   = mh * 64;

    // ---- stage W_hh slice into LDS (once) ----
    {
        const unsigned short* wbase = whh + (size_t)d * GG * HH;
        #pragma unroll
        for (int it = 0; it < 16; it++){
            int idx  = it * 256 + tid;
            int row  = idx >> 6;
            int col8 = idx & 63;
            int g2 = row >> 4, j2 = row & 15;
            short8 v = *(const short8*)(wbase + (size_t)(g2 * 512 + jc * 16 + j2) * HH + col8 * 8);
            *(short8*)&w_s[g2][j2][col8 * 8] = v;
        }
    }
    if (cw != nullptr && tid < NC * 16){
        int c = tid >> 4, j = tid & 15;
        cw_s[c][j] = cw[(size_t)c * 1024 + d * 512 + jc * 16 + j];
    }

    // ---- cstate -> 4 registers ----
    float csreg[4];
    #pragma unroll
    for (int rr = 0; rr < 4; rr++){
        const int gm = m0 + wv * 16 + quad * 4 + rr;
        csreg[rr] = cstate[((size_t)d * BB + gm) * HH + jc * 16 + l15];
    }

    // ---- initial preC prefetch (step 0) ----
    unsigned short pf[4][4];
    {
        const int time0 = d ? (TT - 1 - t0) : t0;
        const int slot0 = time0 & (CH - 1);
        const unsigned short* p0 = preC + (((size_t)(d * CH + slot0)) * BB + (m0 + wv * 16 + quad * 4)) * GG + jc * 16 + l15;
        #pragma unroll
        for (int rr = 0; rr < 4; rr++)
            #pragma unroll
            for (int g = 0; g < 4; g++)
                pf[rr][g] = p0[(size_t)rr * GG + g * 512];
    }
    __syncthreads();   // w_s / cw_s visible to all waves; the ONLY block barrier

    // slab layout per grp: [jc tile 0..31][row 0..63][16 cols]; 8B unit = 4 cols.
    const size_t slabU = (size_t)grp * 8192;               // 8B units
    unsigned int* myFl  = bar + (((size_t)grp * 4 + wv) * 32 + jc) * 16;
    const unsigned int* pollFl = bar + (((size_t)grp * 4 + wv) * 32 + (lane & 31)) * 16;

    const int rowu = (wv * 16 + l15) * 4 + (quad & 1) * 2; // consumer 8B-unit offset within a tile pair
    const int jq   = quad >> 1;

    unsigned short pfN[4][4];

    for (int ls = 0; ls < nsteps; ls++){
        const int tt   = t0 + ls;
        const unsigned long long* srcU = (const unsigned long long*)((tt & 1) ? hB : hA) + slabU;
        unsigned long long*       dstU = (unsigned long long*)((tt & 1) ? hA : hB) + slabU + (size_t)jc * 256;

        // ---- ring wait: my wv's 32 producers have stored h(ls-1) ----
        if (ls > 0){
            const unsigned int tgt = (unsigned int)ls;
            while (__hip_atomic_load(pollFl, __ATOMIC_RELAXED, __HIP_MEMORY_SCOPE_AGENT) < tgt)
                __builtin_amdgcn_s_sleep(1);
            __builtin_amdgcn_fence(__ATOMIC_ACQUIRE, "workgroup");  // compiler ordering only
            #pragma unroll
            for (int rr = 0; rr < 4; rr++)
                #pragma unroll
                for (int g = 0; g < 4; g++)
                    pf[rr][g] = pfN[rr][g];        // wait for prefetch hid under the poll
        }

        // ---- A-fragments: direct global->reg (32 x 8B agent loads) ----
        unsigned long long afr[16][2];
        #pragma unroll
        for (int kk = 0; kk < 16; kk++){
            const unsigned long long* p = srcU + (size_t)(2 * kk + jq) * 256 + rowu;
            afr[kk][0] = __hip_atomic_load(p,     __ATOMIC_RELAXED, __HIP_MEMORY_SCOPE_AGENT);
            afr[kk][1] = __hip_atomic_load(p + 1, __ATOMIC_RELAXED, __HIP_MEMORY_SCOPE_AGENT);
        }

        // ---- MFMA: 16 kk x 4 gates ----
        f32x4 acc[4];
        #pragma unroll
        for (int g = 0; g < 4; g++){ acc[g][0]=0.f; acc[g][1]=0.f; acc[g][2]=0.f; acc[g][3]=0.f; }
        #pragma unroll
        for (int kk = 0; kk < 16; kk++){
            union { unsigned long long u[2]; short8 s; } cv;
            cv.u[0] = afr[kk][0]; cv.u[1] = afr[kk][1];
            const short8 a = cv.s;
            #pragma unroll
            for (int g = 0; g < 4; g++){
                short8 b = *(const short8*)&w_s[g][l15][kk * 32 + quad * 8];
                acc[g] = __builtin_amdgcn_mfma_f32_16x16x32_bf16(a, b, acc[g], 0, 0, 0);
            }
        }

        // ---- gate fusion (4 cells/lane) ----
        #pragma unroll
        for (int rr = 0; rr < 4; rr++){
            const int lr = wv * 16 + quad * 4 + rr;
            const float zi = acc[0][rr] + bf2f(pf[rr][0]);
            const float zf = acc[1][rr] + bf2f(pf[rr][1]);
            const float zg = acc[2][rr] + bf2f(pf[rr][2]);
            const float zo = acc[3][rr] + bf2f(pf[rr][3]);
            float cs = sigm(zf) * csreg[rr] + sigm(zi) * tanh_f(zg);
            csreg[rr] = cs;
            htile[lr][l15] = f2bf(sigm(zo) * tanh_f(cs));
        }
        // wave-internal LDS transpose (lgkmcnt only; own quadrant, no barrier)
        const int trowL = lane >> 2;
        const unsigned long long hv8 = *(const unsigned long long*)&htile[wv * 16 + trowL][(lane & 3) * 4];

        // ---- producer: 512B wave store + own-drain + flag ----
        __hip_atomic_store(dstU + wv * 64 + lane, hv8, __ATOMIC_RELAXED, __HIP_MEMORY_SCOPE_AGENT);
        asm volatile("s_waitcnt vmcnt(0)" ::: "memory");   // my h store visible before flag
        __hip_atomic_store(myFl, (unsigned int)(ls + 1), __ATOMIC_RELAXED, __HIP_MEMORY_SCOPE_AGENT);

        // ---- off-critical-path (hidden under next poll) ----
        const int time = d ? (TT - 1 - tt) : tt;
        const bool more = (ls + 1 < nsteps);

        if (more){
            const int tt1 = tt + 1;
            const int time1 = d ? (TT - 1 - tt1) : tt1;
            const int slot1 = time1 & (CH - 1);
            const unsigned short* p1 = preC + (((size_t)(d * CH + slot1)) * BB + (m0 + wv * 16 + quad * 4)) * GG + jc * 16 + l15;
            #pragma unroll
            for (int rr = 0; rr < 4; rr++)
                #pragma unroll
                for (int g = 0; g < 4; g++)
                    pfN[rr][g] = p1[(size_t)rr * GG + g * 512];
        }

        if (cw == nullptr){
            *(unsigned long long*)(hs_out + ((size_t)time * BB + m0 + wv * 16 + trowL) * (2 * HH) + d * HH + jc * 16 + (lane & 3) * 4) = hv8;
        } else {
            const int part = lane & 3;
            float hvv[4];
            #pragma unroll
            for (int k = 0; k < 4; k++) hvv[k] = bf2f((unsigned short)(hv8 >> (16 * k)));
            float p[NC];
            #pragma unroll
            for (int c = 0; c < NC; c++){
                float s = 0.f;
                #pragma unroll
                for (int k = 0; k < 4; k++) s += hvv[k] * cw_s[c][part * 4 + k];
                p[c] = s;
            }
            #pragma unroll
            for (int c = 0; c < NC; c++){
                p[c] += __shfl_xor(p[c], 1, 64);
                p[c] += __shfl_xor(p[c], 2, 64);
            }
            if (part == 0){
                float* emr = em + ((size_t)time * BB + m0 + wv * 16 + trowL) * NC;
                #pragma unroll
                for (int c = 0; c < NC; c++) atomicAdd(emr + c, p[c]);
            }
        }
    }

    // ---- cstate regs -> global ----
    #pragma unroll
    for (int rr = 0; rr < 4; rr++){
        const int gm = m0 + wv * 16 + quad * 4 + rr;
        cstate[((size_t)d * BB + gm) * HH + jc * 16 + l15] = csreg[rr];
    }
}

// ---------------- em init: em[t,b,c] = cls_b[c] ----------------
__global__ void eminit(const float* __restrict__ cb, float* __restrict__ em){
    int i = blockIdx.x * blockDim.x + threadIdx.x;
    if (i < TB * NC) em[i] = cb[i % NC];
}

// ---------------- CRF per-sequence ----------------
__global__ __launch_bounds__(64) void crf_k(const int* __restrict__ y,
                                            const float* __restrict__ em,
                                            const float* __restrict__ cstart,
                                            const float* __restrict__ cend,
                                            const float* __restrict__ ctr,
                                            float* __restrict__ llh){
    int b = blockIdx.x;
    int lane = threadIdx.x;

    float sp = 0.f; int cnt = 0;
    for (int t = lane; t < TT; t += 64){
        int yt = y[b * TT + t];
        bool mk = (yt > -1);
        cnt += mk ? 1 : 0;
        if (t >= 1 && mk){
            int yp  = y[b * TT + t - 1];
            int tag  = yt > 0 ? yt : 0;
            int tagp = yp > 0 ? yp : 0;
            sp += ctr[tagp * NC + tag] + em[((size_t)t * BB + b) * NC + tag];
        }
    }
    #pragma unroll
    for (int off = 32; off > 0; off >>= 1){
        sp  += __shfl_xor(sp, off, 64);
        cnt += __shfl_xor(cnt, off, 64);
    }

    float trc[NC];
    #pragma unroll
    for (int cc2 = 0; cc2 < NC; cc2++) trc[cc2] = 0.f;
    if (lane < NC){
        #pragma unroll
        for (int cc2 = 0; cc2 < NC; cc2++) trc[cc2] = ctr[cc2 * NC + lane];
    }
    float alpha = -1e30f;
    if (lane < NC) alpha = cstart[lane] + em[(size_t)b * NC + lane];

    for (int t = 1; t < TT; t++){
        int yt = y[b * TT + t];
        bool mk = (yt > -1);
        float e = (lane < NC) ? em[((size_t)t * BB + b) * NC + lane] : 0.f;
        float v[NC]; float mx = -1e30f;
        #pragma unroll
        for (int cc2 = 0; cc2 < NC; cc2++){
            float ac = __shfl(alpha, cc2, 64);
            v[cc2] = ac + trc[cc2];
            mx = fmaxf(mx, v[cc2]);
        }
        float s = 0.f;
        #pragma unroll
        for (int cc2 = 0; cc2 < NC; cc2++) s += __expf(v[cc2] - mx);
        float nxt = mx + __logf(s) + e;
        if (mk && lane < NC) alpha = nxt;
    }

    float val = (lane < NC) ? (alpha + cend[lane]) : -1e30f;
    float mx = -1e30f;
    #pragma unroll
    for (int cc2 = 0; cc2 < NC; cc2++) mx = fmaxf(mx, __shfl(val, cc2, 64));
    float s = 0.f;
    #pragma unroll
    for (int cc2 = 0; cc2 < NC; cc2++) s += __expf(__shfl(val, cc2, 64) - mx);
    float denom = mx + __logf(s);

    if (lane == 0){
        int y0 = y[b * TT];
        int tag0 = y0 > 0 ? y0 : 0;
        int se = cnt - 1;
        if (se < 0) se = 0;
        int yl = y[b * TT + se];
        int tagl = yl > 0 ? yl : 0;
        float score = sp + cstart[tag0] + em[(size_t)b * NC + tag0] + cend[tagl];
        llh[b] = score - denom;
    }
}

__global__ void final_k(const float* __restrict__ llh, float* __restrict__ out){
    __shared__ float sm[128];
    int i = threadIdx.x;
    sm[i] = llh[i];
    __syncthreads();
    for (int s = 64; s > 0; s >>= 1){
        if (i < s) sm[i] += sm[i + s];
        __syncthreads();
    }
    if (i == 0) out[0] = -sm[0] / 128.f;
}

__global__ void sentinel_k(float* out, float v){ out[0] = v; }

extern "C" void kernel_launch(void* const* d_in, const int* in_sizes, int n_in,
                              void* d_out, int out_size, void* d_ws, size_t ws_size,
                              hipStream_t stream) {
    const int*   x     = (const int*)d_in[0];
    const int*   y     = (const int*)d_in[1];
    const float* embed = (const float*)d_in[2];
    const float* wih0  = (const float*)d_in[3];
    const float* whh0  = (const float*)d_in[4];
    const float* b0    = (const float*)d_in[5];
    const float* wih1  = (const float*)d_in[6];
    const float* whh1  = (const float*)d_in[7];
    const float* b1    = (const float*)d_in[8];
    const float* clsw  = (const float*)d_in[9];
    const float* clsb  = (const float*)d_in[10];
    const float* cst   = (const float*)d_in[11];
    const float* cen   = (const float*)d_in[12];
    const float* ctr   = (const float*)d_in[13];
    float* out = (float*)d_out;

    const size_t sz_w0   = (size_t)2 * GG * HH * 2;
    const size_t sz_w1   = (size_t)2 * GG * 1024 * 2;
    const size_t sz_xs   = (size_t)TB * HH * 2;
    const size_t sz_hs0  = (size_t)TB * 1024 * 2;
    const size_t sz_h    = (size_t)2 * BB * HH * 2;
    const size_t sz_c    = (size_t)2 * BB * HH * 4;
    const size_t sz_emis = (size_t)TB * NC * 4;
    const size_t sz_llh  = (size_t)BB * 4;
    const size_t sz_bar  = 32768;         // 4 grp x 4 wv x 32 jc x 64B line
    auto rup = [](size_t v){ return (v + 255) & ~(size_t)255; };
    size_t fixed = rup(sz_w0) * 3 + rup(sz_w1) + rup(sz_xs) + rup(sz_hs0)
                 + rup(sz_h) * 2 + rup(sz_c) + rup(sz_emis) + rup(sz_llh) + rup(sz_bar);

    const int cands[7] = {256, 128, 64, 32, 16, 8, 4};
    int CH = 0;
    for (int i = 0; i < 7; i++){
        size_t need = fixed + rup((size_t)2 * cands[i] * BB * GG * 2);
        if (need <= ws_size){ CH = cands[i]; break; }
    }
    if (CH == 0){
        sentinel_k<<<1, 1, 0, stream>>>(out, -(float)(ws_size >> 20));
        return;
    }

    char* ws = (char*)d_ws;
    size_t off = 0;
    auto alloc = [&](size_t bytes) -> void* {
        void* p = (void*)(ws + off);
        off += (bytes + 255) & ~(size_t)255;
        return p;
    };
    unsigned short* wih0b = (unsigned short*)alloc(sz_w0);
    unsigned short* whh0b = (unsigned short*)alloc(sz_w0);
    unsigned short* whh1b = (unsigned short*)alloc(sz_w0);
    unsigned short* wih1b = (unsigned short*)alloc(sz_w1);
    unsigned short* xs    = (unsigned short*)alloc(sz_xs);
    unsigned short* hs0   = (unsigned short*)alloc(sz_hs0);
    unsigned short* hA    = (unsigned short*)alloc(sz_h);
    unsigned short* hB    = (unsigned short*)alloc(sz_h);
    float*          cbuf  = (float*)alloc(sz_c);
    float*          emis  = (float*)alloc(sz_emis);
    float*          llh   = (float*)alloc(sz_llh);
    unsigned int*   bar   = (unsigned int*)alloc(sz_bar);
    unsigned short* preC  = (unsigned short*)alloc((size_t)2 * CH * BB * GG * 2);

    castbf<<<(2 * GG * HH + 255) / 256, 256, 0, stream>>>(wih0, wih0b, 2 * GG * HH);
    castbf<<<(2 * GG * HH + 255) / 256, 256, 0, stream>>>(whh0, whh0b, 2 * GG * HH);
    castbf<<<(2 * GG * 1024 + 255) / 256, 256, 0, stream>>>(wih1, wih1b, 2 * GG * 1024);
    castbf<<<(2 * GG * HH + 255) / 256, 256, 0, stream>>>(whh1, whh1b, 2 * GG * HH);

    embed_k<<<TB / 4, 256, 0, stream>>>(x, embed, xs);

    const int nch = TT / CH;

    // ---------- layer 0 (writes hs0) ----------
    (void)hipMemsetAsync(hA, 0, sz_h, stream);
    (void)hipMemsetAsync(cbuf, 0, sz_c, stream);
    for (int c = 0; c < nch; c++){
        int t0f = c * CH;
        int t0b = TT - (c + 1) * CH;
        gemm2<<<dim3(CH, GG / 128, 2), 256, 0, stream>>>(
            xs + (size_t)t0f * BB * HH, xs + (size_t)t0b * BB * HH,
            wih0b, b0, preC, HH, CH);
        (void)hipMemsetAsync(bar, 0, sz_bar, stream);
        lstm_seq<<<128, 256, 0, stream>>>(preC, whh0b, hA, hB, cbuf, hs0,
                                          nullptr, emis, c * CH, CH, CH, bar);
    }

    // ---------- emissions init ----------
    eminit<<<(TB * NC + 255) / 256, 256, 0, stream>>>(clsb, emis);

    // ---------- layer 1 (fused emissions, no hs1) ----------
    (void)hipMemsetAsync(hA, 0, sz_h, stream);
    (void)hipMemsetAsync(cbuf, 0, sz_c, stream);
    for (int c = 0; c < nch; c++){
        int t0f = c * CH;
        int t0b = TT - (c + 1) * CH;
        gemm2<<<dim3(CH, GG / 128, 2), 256, 0, stream>>>(
            hs0 + (size_t)t0f * BB * 1024, hs0 + (size_t)t0b * BB * 1024,
            wih1b, b1, preC, 1024, CH);
        (void)hipMemsetAsync(bar, 0, sz_bar, stream);
        lstm_seq<<<128, 256, 0, stream>>>(preC, whh1b, hA, hB, cbuf, hs0,
                                          clsw, emis, c * CH, CH, CH, bar);
    }

    crf_k<<<BB, 64, 0, stream>>>(y, emis, cst, cen, ctr, llh);
    final_k<<<1, 128, 0, stream>>>(llh, out);
}

// Round 5
// 4694.271 us; speedup vs baseline: 1.9386x; 1.0683x over previous
//
#include <hip/hip_runtime.h>
#include <hip/hip_bf16.h>

#define VV 30000
#define HH 512
#define NC 9
#define BB 128
#define TT 256
#define GG 2048
#define TB (TT*BB)

using short8 = __attribute__((ext_vector_type(8))) short;
using f32x4  = __attribute__((ext_vector_type(4))) float;

__device__ inline float bf2f(unsigned short u){
    union { unsigned int i; float f; } v; v.i = ((unsigned int)u) << 16; return v.f;
}
__device__ inline unsigned short f2bf(float f){
    union { unsigned int i; float f; } v; v.f = f;
    unsigned int x = v.i;
    unsigned int r = (x + 0x7fffu + ((x >> 16) & 1u)) >> 16;
    return (unsigned short)r;
}
__device__ inline float sigm(float x){
    if (x >= 0.f){ return 1.f / (1.f + __expf(-x)); }
    float e = __expf(x); return e / (1.f + e);
}
__device__ inline float tanh_f(float x){
    float ax = fabsf(x);
    float e = __expf(-2.f * ax);
    float t = (1.f - e) / (1.f + e);
    return copysignf(t, x);
}

// ---------------- weight cast fp32 -> bf16 ----------------
__global__ void castbf(const float* __restrict__ in, unsigned short* __restrict__ out, int n){
    int i = blockIdx.x * blockDim.x + threadIdx.x;
    if (i < n) out[i] = f2bf(in[i]);
}

// ---------------- embedding + renorm -> xs bf16 [T*B][H] ----------------
__global__ __launch_bounds__(256) void embed_k(const int* __restrict__ x,
                                               const float* __restrict__ embed,
                                               unsigned short* __restrict__ xs){
    int wid  = (int)((blockIdx.x * blockDim.x + threadIdx.x) >> 6);
    int lane = threadIdx.x & 63;
    if (wid >= TB) return;
    int t = wid >> 7, b = wid & 127;
    int tok = x[b * TT + t];
    const float4* e = (const float4*)(embed + (size_t)tok * HH);
    float4 v0 = e[lane], v1 = e[lane + 64];
    float ss = v0.x*v0.x + v0.y*v0.y + v0.z*v0.z + v0.w*v0.w
             + v1.x*v1.x + v1.y*v1.y + v1.z*v1.z + v1.w*v1.w;
    #pragma unroll
    for (int off = 32; off > 0; off >>= 1) ss += __shfl_xor(ss, off, 64);
    float nrm = sqrtf(ss);
    float sc = (nrm > 1.f) ? 1.f / (nrm + 1e-7f) : 1.f;
    unsigned short* dst = xs + (size_t)wid * HH;
    ushort4 o0, o1;
    o0.x = f2bf(v0.x * sc); o0.y = f2bf(v0.y * sc); o0.z = f2bf(v0.z * sc); o0.w = f2bf(v0.w * sc);
    o1.x = f2bf(v1.x * sc); o1.y = f2bf(v1.y * sc); o1.z = f2bf(v1.z * sc); o1.w = f2bf(v1.w * sc);
    ((ushort4*)dst)[lane]      = o0;
    ((ushort4*)dst)[lane + 64] = o1;
}

// ---------------- bf16 GEMM (both dirs via blockIdx.z): C = A@W^T + bias ----------------
// 128x128 tile, BK=32, double-buffered global_load_lds with counted vmcnt(4);
// bijective XCD-chunk swizzle; epilogue bounced through LDS for 16B stores.
__global__ __launch_bounds__(256) void gemm2(const unsigned short* __restrict__ A0,
                                             const unsigned short* __restrict__ A1,
                                             const unsigned short* __restrict__ Wb_,
                                             const float* __restrict__ bias,
                                             unsigned short* __restrict__ Cout,
                                             int K, int CH){
    const int dz = blockIdx.z;
    const unsigned short* A  = dz ? A1 : A0;
    const unsigned short* W  = Wb_ + (size_t)dz * GG * K;
    const float*          bd = bias + dz * GG;
    unsigned short*       C  = Cout + (size_t)dz * CH * BB * GG;

    __shared__ __align__(16) unsigned short smem[16384];

    const int tid  = threadIdx.x;
    const int lane = tid & 63;
    const int wv   = tid >> 6;
    const int l15  = lane & 15, quad = lane >> 4;
    const int mw   = (wv >> 1) * 64;
    const int nw   = (wv & 1) * 64;

    const int nwg   = gridDim.x * gridDim.y;
    const int chunk = nwg >> 3;
    const int id    = blockIdx.x + gridDim.x * blockIdx.y;
    const int nid   = (id & 7) * chunk + (id >> 3);
    const int m0    = (nid % gridDim.x) * 128;
    const int n0    = (nid / gridDim.x) * 128;

    const int srow = lane >> 2;
    const int scol = (lane & 3) * 8;
    const int c0 = wv * 2, c1 = wv * 2 + 1;
    const unsigned short* gA0 = A + (size_t)(m0 + c0 * 16 + srow) * K + scol;
    const unsigned short* gA1 = A + (size_t)(m0 + c1 * 16 + srow) * K + scol;
    const unsigned short* gB0 = W + (size_t)(n0 + c0 * 16 + srow) * K + scol;
    const unsigned short* gB1 = W + (size_t)(n0 + c1 * 16 + srow) * K + scol;

    f32x4 acc[4][4];
    #pragma unroll
    for (int i = 0; i < 4; i++)
        #pragma unroll
        for (int j = 0; j < 4; j++){ acc[i][j][0]=0.f; acc[i][j][1]=0.f; acc[i][j][2]=0.f; acc[i][j][3]=0.f; }

    #define STAGE(bufi, kko)                                                                              \
        do {                                                                                              \
            __builtin_amdgcn_global_load_lds((const __attribute__((address_space(1))) void*)(gA0 + (kko)),\
                (__attribute__((address_space(3))) void*)(smem + (bufi) * 4096 + c0 * 512), 16, 0, 0);    \
            __builtin_amdgcn_global_load_lds((const __attribute__((address_space(1))) void*)(gA1 + (kko)),\
                (__attribute__((address_space(3))) void*)(smem + (bufi) * 4096 + c1 * 512), 16, 0, 0);    \
            __builtin_amdgcn_global_load_lds((const __attribute__((address_space(1))) void*)(gB0 + (kko)),\
                (__attribute__((address_space(3))) void*)(smem + 8192 + (bufi) * 4096 + c0 * 512), 16, 0, 0);\
            __builtin_amdgcn_global_load_lds((const __attribute__((address_space(1))) void*)(gB1 + (kko)),\
                (__attribute__((address_space(3))) void*)(smem + 8192 + (bufi) * 4096 + c1 * 512), 16, 0, 0);\
        } while (0)

    const int nk = K >> 5;
    STAGE(0, 0);
    for (int t = 0; t < nk; ++t){
        const int buf = t & 1;
        const bool more = (t + 1 < nk);
        if (more){
            STAGE((t + 1) & 1, (t + 1) << 5);
            __builtin_amdgcn_sched_barrier(0);
            asm volatile("s_waitcnt vmcnt(4)" ::: "memory");
        } else {
            __builtin_amdgcn_sched_barrier(0);
            asm volatile("s_waitcnt vmcnt(0)" ::: "memory");
        }
        __builtin_amdgcn_s_barrier();
        __builtin_amdgcn_sched_barrier(0);

        short8 a[4], b[4];
        #pragma unroll
        for (int i = 0; i < 4; i++) a[i] = *(const short8*)&smem[(size_t)buf * 4096 + (mw + i * 16 + l15) * 32 + quad * 8];
        #pragma unroll
        for (int j = 0; j < 4; j++) b[j] = *(const short8*)&smem[8192 + (size_t)buf * 4096 + (nw + j * 16 + l15) * 32 + quad * 8];
        #pragma unroll
        for (int i = 0; i < 4; i++)
            #pragma unroll
            for (int j = 0; j < 4; j++)
                acc[i][j] = __builtin_amdgcn_mfma_f32_16x16x32_bf16(a[i], b[j], acc[i][j], 0, 0, 0);

        __builtin_amdgcn_sched_barrier(0);
        __builtin_amdgcn_s_barrier();
        __builtin_amdgcn_sched_barrier(0);
    }
    #undef STAGE

    #pragma unroll
    for (int i = 0; i < 4; i++){
        #pragma unroll
        for (int j = 0; j < 4; j++){
            const int ncol = nw + j * 16 + l15;
            const float bn = bd[n0 + ncol];
            #pragma unroll
            for (int r = 0; r < 4; r++){
                const int mrow = mw + i * 16 + quad * 4 + r;
                smem[mrow * 128 + ncol] = f2bf(acc[i][j][r] + bn);
            }
        }
    }
    __syncthreads();
    #pragma unroll
    for (int it = 0; it < 8; it++){
        const int ch  = it * 256 + tid;
        const int row = ch >> 4;
        const int col = (ch & 15) * 8;
        *(short8*)(C + (size_t)(m0 + row) * GG + n0 + col) = *(const short8*)&smem[row * 128 + col];
    }
}

// ---------------- fused: BiLSTM rings (blocks 0-127, round-3 verified code)
//                  + helper gemm for NEXT chunk (blocks 128+) ----------------
// Rings read preC (parity c); helpers write Cnext (parity c^1). Disjoint
// buffers, no ring<->helper sync; ordering by dispatch boundaries. LDS is a
// 69.9KB arena aliased by both paths -> 2 blocks/CU, all 384 co-resident.
__global__ __launch_bounds__(256) void lstm_fused(const unsigned short* __restrict__ preC, // [2][CH][128][2048] (parity c)
                                                  const unsigned short* __restrict__ whh,  // [2][2048][512]
                                                  unsigned short* __restrict__ hA,
                                                  unsigned short* __restrict__ hB,
                                                  float* __restrict__ cstate,
                                                  unsigned short* __restrict__ hs_out,
                                                  const float* __restrict__ cw,
                                                  float* __restrict__ em,
                                                  int t0, int nsteps, int CH,
                                                  unsigned int* __restrict__ bar,
                                                  const unsigned short* __restrict__ An0,  // next-chunk A fwd (or null)
                                                  const unsigned short* __restrict__ An1,  // next-chunk A bwd
                                                  const unsigned short* __restrict__ Wi_,  // [2][2048][K] W_ih
                                                  const float* __restrict__ bias,
                                                  unsigned short* __restrict__ Cnext,      // parity c^1
                                                  int K, int njobs){
    __shared__ __align__(16) unsigned char shm[69888];

    const int tid  = threadIdx.x;
    const int bx   = blockIdx.x;

    if (bx < 128){
        // ======== RING PATH — byte-identical logic to round-3 verified kernel ========
        unsigned short (*w_s)[16][520] = (unsigned short (*)[16][520])shm;        // 66560 B
        unsigned short (*htile)[20]    = (unsigned short (*)[20])(shm + 66560);   //  2560 B
        float (*cw_s)[16]              = (float (*)[16])(shm + 69120);            //   576 B

        const int lane = tid & 63;
        const int wv   = tid >> 6;
        const int l15  = lane & 15, quad = lane >> 4;
        const int grp  = bx & 3;          // (d, mh)
        const int d    = grp >> 1;
        const int mh   = grp & 1;
        const int jc   = bx >> 2;         // 0..31
        const int m0   = mh * 64;

        // ---- stage W_hh slice into LDS (once) ----
        {
            const unsigned short* wbase = whh + (size_t)d * GG * HH;
            #pragma unroll
            for (int it = 0; it < 16; it++){
                int idx  = it * 256 + tid;
                int row  = idx >> 6;
                int col8 = idx & 63;
                int g2 = row >> 4, j2 = row & 15;
                short8 v = *(const short8*)(wbase + (size_t)(g2 * 512 + jc * 16 + j2) * HH + col8 * 8);
                *(short8*)&w_s[g2][j2][col8 * 8] = v;
            }
        }
        if (cw != nullptr && tid < NC * 16){
            int c = tid >> 4, j = tid & 15;
            cw_s[c][j] = cw[(size_t)c * 1024 + d * 512 + jc * 16 + j];
        }

        // ---- cstate -> 4 registers ----
        float csreg[4];
        #pragma unroll
        for (int rr = 0; rr < 4; rr++){
            const int gm = m0 + wv * 16 + quad * 4 + rr;
            csreg[rr] = cstate[((size_t)d * BB + gm) * HH + jc * 16 + l15];
        }

        // ---- initial preC prefetch (step 0) ----
        unsigned short pf[4][4];
        {
            const int time0 = d ? (TT - 1 - t0) : t0;
            const int slot0 = time0 & (CH - 1);
            const unsigned short* p0 = preC + (((size_t)(d * CH + slot0)) * BB + (m0 + wv * 16 + quad * 4)) * GG + jc * 16 + l15;
            #pragma unroll
            for (int rr = 0; rr < 4; rr++)
                #pragma unroll
                for (int g = 0; g < 4; g++)
                    pf[rr][g] = p0[(size_t)rr * GG + g * 512];
        }
        __syncthreads();   // w_s / cw_s visible; the only block barrier

        const size_t slabU = (size_t)grp * 8192;               // 8B units
        unsigned int* myFl  = bar + (((size_t)grp * 4 + wv) * 32 + jc) * 16;
        const unsigned int* pollFl = bar + (((size_t)grp * 4 + wv) * 32 + (lane & 31)) * 16;

        const int rowu = (wv * 16 + l15) * 4 + (quad & 1) * 2;
        const int jq   = quad >> 1;

        unsigned short pfN[4][4];

        for (int ls = 0; ls < nsteps; ls++){
            const int tt   = t0 + ls;
            const unsigned long long* srcU = (const unsigned long long*)((tt & 1) ? hB : hA) + slabU;
            unsigned long long*       dstU = (unsigned long long*)((tt & 1) ? hA : hB) + slabU + (size_t)jc * 256;

            // ---- ring wait ----
            if (ls > 0){
                const unsigned int tgt = (unsigned int)ls;
                while (__hip_atomic_load(pollFl, __ATOMIC_RELAXED, __HIP_MEMORY_SCOPE_AGENT) < tgt)
                    __builtin_amdgcn_s_sleep(1);
                __builtin_amdgcn_fence(__ATOMIC_ACQUIRE, "workgroup");
                #pragma unroll
                for (int rr = 0; rr < 4; rr++)
                    #pragma unroll
                    for (int g = 0; g < 4; g++)
                        pf[rr][g] = pfN[rr][g];
            }

            // ---- A-fragments: direct global->reg (32 x 8B agent loads) ----
            unsigned long long afr[16][2];
            #pragma unroll
            for (int kk = 0; kk < 16; kk++){
                const unsigned long long* p = srcU + (size_t)(2 * kk + jq) * 256 + rowu;
                afr[kk][0] = __hip_atomic_load(p,     __ATOMIC_RELAXED, __HIP_MEMORY_SCOPE_AGENT);
                afr[kk][1] = __hip_atomic_load(p + 1, __ATOMIC_RELAXED, __HIP_MEMORY_SCOPE_AGENT);
            }

            // ---- MFMA: 16 kk x 4 gates ----
            f32x4 acc[4];
            #pragma unroll
            for (int g = 0; g < 4; g++){ acc[g][0]=0.f; acc[g][1]=0.f; acc[g][2]=0.f; acc[g][3]=0.f; }
            #pragma unroll
            for (int kk = 0; kk < 16; kk++){
                union { unsigned long long u[2]; short8 s; } cv;
                cv.u[0] = afr[kk][0]; cv.u[1] = afr[kk][1];
                const short8 a = cv.s;
                #pragma unroll
                for (int g = 0; g < 4; g++){
                    short8 b = *(const short8*)&w_s[g][l15][kk * 32 + quad * 8];
                    acc[g] = __builtin_amdgcn_mfma_f32_16x16x32_bf16(a, b, acc[g], 0, 0, 0);
                }
            }

            // ---- gate fusion (4 cells/lane) ----
            #pragma unroll
            for (int rr = 0; rr < 4; rr++){
                const int lr = wv * 16 + quad * 4 + rr;
                const float zi = acc[0][rr] + bf2f(pf[rr][0]);
                const float zf = acc[1][rr] + bf2f(pf[rr][1]);
                const float zg = acc[2][rr] + bf2f(pf[rr][2]);
                const float zo = acc[3][rr] + bf2f(pf[rr][3]);
                float cs = sigm(zf) * csreg[rr] + sigm(zi) * tanh_f(zg);
                csreg[rr] = cs;
                htile[lr][l15] = f2bf(sigm(zo) * tanh_f(cs));
            }
            const int trowL = lane >> 2;
            const unsigned long long hv8 = *(const unsigned long long*)&htile[wv * 16 + trowL][(lane & 3) * 4];

            // ---- producer: 512B wave store + own-drain + flag ----
            __hip_atomic_store(dstU + wv * 64 + lane, hv8, __ATOMIC_RELAXED, __HIP_MEMORY_SCOPE_AGENT);
            asm volatile("s_waitcnt vmcnt(0)" ::: "memory");
            __hip_atomic_store(myFl, (unsigned int)(ls + 1), __ATOMIC_RELAXED, __HIP_MEMORY_SCOPE_AGENT);

            // ---- off-critical-path (hidden under next poll) ----
            const int time = d ? (TT - 1 - tt) : tt;
            const bool more = (ls + 1 < nsteps);

            if (more){
                const int tt1 = tt + 1;
                const int time1 = d ? (TT - 1 - tt1) : tt1;
                const int slot1 = time1 & (CH - 1);
                const unsigned short* p1 = preC + (((size_t)(d * CH + slot1)) * BB + (m0 + wv * 16 + quad * 4)) * GG + jc * 16 + l15;
                #pragma unroll
                for (int rr = 0; rr < 4; rr++)
                    #pragma unroll
                    for (int g = 0; g < 4; g++)
                        pfN[rr][g] = p1[(size_t)rr * GG + g * 512];
            }

            if (cw == nullptr){
                *(unsigned long long*)(hs_out + ((size_t)time * BB + m0 + wv * 16 + trowL) * (2 * HH) + d * HH + jc * 16 + (lane & 3) * 4) = hv8;
            } else {
                const int part = lane & 3;
                float hvv[4];
                #pragma unroll
                for (int k = 0; k < 4; k++) hvv[k] = bf2f((unsigned short)(hv8 >> (16 * k)));
                float p[NC];
                #pragma unroll
                for (int c = 0; c < NC; c++){
                    float s = 0.f;
                    #pragma unroll
                    for (int k = 0; k < 4; k++) s += hvv[k] * cw_s[c][part * 4 + k];
                    p[c] = s;
                }
                #pragma unroll
                for (int c = 0; c < NC; c++){
                    p[c] += __shfl_xor(p[c], 1, 64);
                    p[c] += __shfl_xor(p[c], 2, 64);
                }
                if (part == 0){
                    float* emr = em + ((size_t)time * BB + m0 + wv * 16 + trowL) * NC;
                    #pragma unroll
                    for (int c = 0; c < NC; c++) atomicAdd(emr + c, p[c]);
                }
            }
        }

        // ---- cstate regs -> global ----
        #pragma unroll
        for (int rr = 0; rr < 4; rr++){
            const int gm = m0 + wv * 16 + quad * 4 + rr;
            cstate[((size_t)d * BB + gm) * HH + jc * 16 + l15] = csreg[rr];
        }
        return;
    }

    // ======== HELPER PATH: gemm tile-jobs for the NEXT chunk ========
    if (An0 == nullptr) return;
    unsigned short* smem = (unsigned short*)shm;   // 32 KB staging + C-bounce

    const int lane = tid & 63;
    const int wv   = tid >> 6;
    const int l15  = lane & 15, quad = lane >> 4;
    const int mw   = (wv >> 1) * 64;
    const int nw   = (wv & 1) * 64;
    const int srow = lane >> 2;
    const int scol = (lane & 3) * 8;
    const int c0 = wv * 2, c1 = wv * 2 + 1;
    const int nhb = (int)gridDim.x - 128;
    const int CHn = nsteps;

    for (int job = bx - 128; job < njobs; job += nhb){
        const int xj  = job % CHn;
        const int rem = job / CHn;
        const int yj  = rem & 15;
        const int dz  = rem >> 4;
        const unsigned short* A  = dz ? An1 : An0;
        const unsigned short* W  = Wi_ + (size_t)dz * GG * K;
        const float*          bd = bias + dz * GG;
        unsigned short*       C  = Cnext + (size_t)dz * CHn * BB * GG;
        const int m0 = xj * 128;
        const int n0 = yj * 128;

        const unsigned short* gA0 = A + (size_t)(m0 + c0 * 16 + srow) * K + scol;
        const unsigned short* gA1 = A + (size_t)(m0 + c1 * 16 + srow) * K + scol;
        const unsigned short* gB0 = W + (size_t)(n0 + c0 * 16 + srow) * K + scol;
        const unsigned short* gB1 = W + (size_t)(n0 + c1 * 16 + srow) * K + scol;

        f32x4 acc[4][4];
        #pragma unroll
        for (int i = 0; i < 4; i++)
            #pragma unroll
            for (int j = 0; j < 4; j++){ acc[i][j][0]=0.f; acc[i][j][1]=0.f; acc[i][j][2]=0.f; acc[i][j][3]=0.f; }

        #define HSTAGE(bufi, kko)                                                                             \
            do {                                                                                              \
                __builtin_amdgcn_global_load_lds((const __attribute__((address_space(1))) void*)(gA0 + (kko)),\
                    (__attribute__((address_space(3))) void*)(smem + (bufi) * 4096 + c0 * 512), 16, 0, 0);    \
                __builtin_amdgcn_global_load_lds((const __attribute__((address_space(1))) void*)(gA1 + (kko)),\
                    (__attribute__((address_space(3))) void*)(smem + (bufi) * 4096 + c1 * 512), 16, 0, 0);    \
                __builtin_amdgcn_global_load_lds((const __attribute__((address_space(1))) void*)(gB0 + (kko)),\
                    (__attribute__((address_space(3))) void*)(smem + 8192 + (bufi) * 4096 + c0 * 512), 16, 0, 0);\
                __builtin_amdgcn_global_load_lds((const __attribute__((address_space(1))) void*)(gB1 + (kko)),\
                    (__attribute__((address_space(3))) void*)(smem + 8192 + (bufi) * 4096 + c1 * 512), 16, 0, 0);\
            } while (0)

        const int nk = K >> 5;
        HSTAGE(0, 0);
        for (int t = 0; t < nk; ++t){
            const int buf = t & 1;
            const bool more = (t + 1 < nk);
            if (more){
                HSTAGE((t + 1) & 1, (t + 1) << 5);
                __builtin_amdgcn_sched_barrier(0);
                asm volatile("s_waitcnt vmcnt(4)" ::: "memory");
            } else {
                __builtin_amdgcn_sched_barrier(0);
                asm volatile("s_waitcnt vmcnt(0)" ::: "memory");
            }
            __builtin_amdgcn_s_barrier();
            __builtin_amdgcn_sched_barrier(0);

            short8 a[4], b[4];
            #pragma unroll
            for (int i = 0; i < 4; i++) a[i] = *(const short8*)&smem[(size_t)buf * 4096 + (mw + i * 16 + l15) * 32 + quad * 8];
            #pragma unroll
            for (int j = 0; j < 4; j++) b[j] = *(const short8*)&smem[8192 + (size_t)buf * 4096 + (nw + j * 16 + l15) * 32 + quad * 8];
            #pragma unroll
            for (int i = 0; i < 4; i++)
                #pragma unroll
                for (int j = 0; j < 4; j++)
                    acc[i][j] = __builtin_amdgcn_mfma_f32_16x16x32_bf16(a[i], b[j], acc[i][j], 0, 0, 0);

            __builtin_amdgcn_sched_barrier(0);
            __builtin_amdgcn_s_barrier();
            __builtin_amdgcn_sched_barrier(0);
        }
        #undef HSTAGE

        #pragma unroll
        for (int i = 0; i < 4; i++){
            #pragma unroll
            for (int j = 0; j < 4; j++){
                const int ncol = nw + j * 16 + l15;
                const float bn = bd[n0 + ncol];
                #pragma unroll
                for (int r = 0; r < 4; r++){
                    const int mrow = mw + i * 16 + quad * 4 + r;
                    smem[mrow * 128 + ncol] = f2bf(acc[i][j][r] + bn);
                }
            }
        }
        __syncthreads();
        #pragma unroll
        for (int it = 0; it < 8; it++){
            const int ch  = it * 256 + tid;
            const int row = ch >> 4;
            const int col = (ch & 15) * 8;
            *(short8*)(C + (size_t)(m0 + row) * GG + n0 + col) = *(const short8*)&smem[row * 128 + col];
        }
        __syncthreads();   // C-bounce reads done before next job's staging
    }
}

// ---------------- em init: em[t,b,c] = cls_b[c] ----------------
__global__ void eminit(const float* __restrict__ cb, float* __restrict__ em){
    int i = blockIdx.x * blockDim.x + threadIdx.x;
    if (i < TB * NC) em[i] = cb[i % NC];
}

// ---------------- CRF per-sequence ----------------
__global__ __launch_bounds__(64) void crf_k(const int* __restrict__ y,
                                            const float* __restrict__ em,
                                            const float* __restrict__ cstart,
                                            const float* __restrict__ cend,
                                            const float* __restrict__ ctr,
                                            float* __restrict__ llh){
    int b = blockIdx.x;
    int lane = threadIdx.x;

    float sp = 0.f; int cnt = 0;
    for (int t = lane; t < TT; t += 64){
        int yt = y[b * TT + t];
        bool mk = (yt > -1);
        cnt += mk ? 1 : 0;
        if (t >= 1 && mk){
            int yp  = y[b * TT + t - 1];
            int tag  = yt > 0 ? yt : 0;
            int tagp = yp > 0 ? yp : 0;
            sp += ctr[tagp * NC + tag] + em[((size_t)t * BB + b) * NC + tag];
        }
    }
    #pragma unroll
    for (int off = 32; off > 0; off >>= 1){
        sp  += __shfl_xor(sp, off, 64);
        cnt += __shfl_xor(cnt, off, 64);
    }

    float trc[NC];
    #pragma unroll
    for (int cc2 = 0; cc2 < NC; cc2++) trc[cc2] = 0.f;
    if (lane < NC){
        #pragma unroll
        for (int cc2 = 0; cc2 < NC; cc2++) trc[cc2] = ctr[cc2 * NC + lane];
    }
    float alpha = -1e30f;
    if (lane < NC) alpha = cstart[lane] + em[(size_t)b * NC + lane];

    for (int t = 1; t < TT; t++){
        int yt = y[b * TT + t];
        bool mk = (yt > -1);
        float e = (lane < NC) ? em[((size_t)t * BB + b) * NC + lane] : 0.f;
        float v[NC]; float mx = -1e30f;
        #pragma unroll
        for (int cc2 = 0; cc2 < NC; cc2++){
            float ac = __shfl(alpha, cc2, 64);
            v[cc2] = ac + trc[cc2];
            mx = fmaxf(mx, v[cc2]);
        }
        float s = 0.f;
        #pragma unroll
        for (int cc2 = 0; cc2 < NC; cc2++) s += __expf(v[cc2] - mx);
        float nxt = mx + __logf(s) + e;
        if (mk && lane < NC) alpha = nxt;
    }

    float val = (lane < NC) ? (alpha + cend[lane]) : -1e30f;
    float mx = -1e30f;
    #pragma unroll
    for (int cc2 = 0; cc2 < NC; cc2++) mx = fmaxf(mx, __shfl(val, cc2, 64));
    float s = 0.f;
    #pragma unroll
    for (int cc2 = 0; cc2 < NC; cc2++) s += __expf(__shfl(val, cc2, 64) - mx);
    float denom = mx + __logf(s);

    if (lane == 0){
        int y0 = y[b * TT];
        int tag0 = y0 > 0 ? y0 : 0;
        int se = cnt - 1;
        if (se < 0) se = 0;
        int yl = y[b * TT + se];
        int tagl = yl > 0 ? yl : 0;
        float score = sp + cstart[tag0] + em[(size_t)b * NC + tag0] + cend[tagl];
        llh[b] = score - denom;
    }
}

__global__ void final_k(const float* __restrict__ llh, float* __restrict__ out){
    __shared__ float sm[128];
    int i = threadIdx.x;
    sm[i] = llh[i];
    __syncthreads();
    for (int s = 64; s > 0; s >>= 1){
        if (i < s) sm[i] += sm[i + s];
        __syncthreads();
    }
    if (i == 0) out[0] = -sm[0] / 128.f;
}

__global__ void sentinel_k(float* out, float v){ out[0] = v; }

extern "C" void kernel_launch(void* const* d_in, const int* in_sizes, int n_in,
                              void* d_out, int out_size, void* d_ws, size_t ws_size,
                              hipStream_t stream) {
    const int*   x     = (const int*)d_in[0];
    const int*   y     = (const int*)d_in[1];
    const float* embed = (const float*)d_in[2];
    const float* wih0  = (const float*)d_in[3];
    const float* whh0  = (const float*)d_in[4];
    const float* b0    = (const float*)d_in[5];
    const float* wih1  = (const float*)d_in[6];
    const float* whh1  = (const float*)d_in[7];
    const float* b1    = (const float*)d_in[8];
    const float* clsw  = (const float*)d_in[9];
    const float* clsb  = (const float*)d_in[10];
    const float* cst   = (const float*)d_in[11];
    const float* cen   = (const float*)d_in[12];
    const float* ctr   = (const float*)d_in[13];
    float* out = (float*)d_out;

    const size_t sz_w0   = (size_t)2 * GG * HH * 2;
    const size_t sz_w1   = (size_t)2 * GG * 1024 * 2;
    const size_t sz_xs   = (size_t)TB * HH * 2;
    const size_t sz_hs0  = (size_t)TB * 1024 * 2;
    const size_t sz_h    = (size_t)2 * BB * HH * 2;
    const size_t sz_c    = (size_t)2 * BB * HH * 4;
    const size_t sz_emis = (size_t)TB * NC * 4;
    const size_t sz_llh  = (size_t)BB * 4;
    const size_t sz_bar  = 32768;
    auto rup = [](size_t v){ return (v + 255) & ~(size_t)255; };
    size_t fixed = rup(sz_w0) * 3 + rup(sz_w1) + rup(sz_xs) + rup(sz_hs0)
                 + rup(sz_h) * 2 + rup(sz_c) + rup(sz_emis) + rup(sz_llh) + rup(sz_bar);

    const int cands[4] = {64, 32, 16, 8};
    int CH = 0;
    for (int i = 0; i < 4; i++){
        size_t par = (size_t)2 * cands[i] * BB * GG * 2;
        if (fixed + 2 * rup(par) <= ws_size){ CH = cands[i]; break; }
    }
    if (CH == 0){
        sentinel_k<<<1, 1, 0, stream>>>(out, -(float)(ws_size >> 20));
        return;
    }
    const size_t parSz = (size_t)2 * CH * BB * GG * 2;

    char* ws = (char*)d_ws;
    size_t off = 0;
    auto alloc = [&](size_t bytes) -> void* {
        void* p = (void*)(ws + off);
        off += (bytes + 255) & ~(size_t)255;
        return p;
    };
    unsigned short* wih0b = (unsigned short*)alloc(sz_w0);
    unsigned short* whh0b = (unsigned short*)alloc(sz_w0);
    unsigned short* whh1b = (unsigned short*)alloc(sz_w0);
    unsigned short* wih1b = (unsigned short*)alloc(sz_w1);
    unsigned short* xs    = (unsigned short*)alloc(sz_xs);
    unsigned short* hs0   = (unsigned short*)alloc(sz_hs0);
    unsigned short* hA    = (unsigned short*)alloc(sz_h);
    unsigned short* hB    = (unsigned short*)alloc(sz_h);
    float*          cbuf  = (float*)alloc(sz_c);
    float*          emis  = (float*)alloc(sz_emis);
    float*          llh   = (float*)alloc(sz_llh);
    unsigned int*   bar   = (unsigned int*)alloc(sz_bar);
    unsigned short* preC0 = (unsigned short*)alloc(parSz);
    unsigned short* preC1 = (unsigned short*)alloc(parSz);

    castbf<<<(2 * GG * HH + 255) / 256, 256, 0, stream>>>(wih0, wih0b, 2 * GG * HH);
    castbf<<<(2 * GG * HH + 255) / 256, 256, 0, stream>>>(whh0, whh0b, 2 * GG * HH);
    castbf<<<(2 * GG * 1024 + 255) / 256, 256, 0, stream>>>(wih1, wih1b, 2 * GG * 1024);
    castbf<<<(2 * GG * HH + 255) / 256, 256, 0, stream>>>(whh1, whh1b, 2 * GG * HH);

    embed_k<<<TB / 4, 256, 0, stream>>>(x, embed, xs);

    const int nch = TT / CH;
    const int njobs = CH * 16 * 2;

    // ---------- emissions init (before any layer-1 atomics) ----------
    eminit<<<(TB * NC + 255) / 256, 256, 0, stream>>>(clsb, emis);

    // ---------- layer 0 (writes hs0) ----------
    (void)hipMemsetAsync(hA, 0, sz_h, stream);
    (void)hipMemsetAsync(cbuf, 0, sz_c, stream);
    gemm2<<<dim3(CH, GG / 128, 2), 256, 0, stream>>>(
        xs, xs + (size_t)(TT - CH) * BB * HH, wih0b, b0, preC0, HH, CH);
    for (int c = 0; c < nch; c++){
        unsigned short* cur = (c & 1) ? preC1 : preC0;
        unsigned short* nxt = (c & 1) ? preC0 : preC1;
        const bool more = (c + 1 < nch);
        (void)hipMemsetAsync(bar, 0, sz_bar, stream);
        lstm_fused<<<384, 256, 0, stream>>>(cur, whh0b, hA, hB, cbuf, hs0,
            nullptr, emis, c * CH, CH, CH, bar,
            more ? xs + (size_t)(c + 1) * CH * BB * HH : nullptr,
            more ? xs + (size_t)(TT - (size_t)(c + 2) * CH) * BB * HH : nullptr,
            wih0b, b0, nxt, HH, njobs);
    }

    // ---------- layer 1 (fused emissions, no hs1) ----------
    (void)hipMemsetAsync(hA, 0, sz_h, stream);
    (void)hipMemsetAsync(cbuf, 0, sz_c, stream);
    gemm2<<<dim3(CH, GG / 128, 2), 256, 0, stream>>>(
        hs0, hs0 + (size_t)(TT - CH) * BB * 1024, wih1b, b1, preC0, 1024, CH);
    for (int c = 0; c < nch; c++){
        unsigned short* cur = (c & 1) ? preC1 : preC0;
        unsigned short* nxt = (c & 1) ? preC0 : preC1;
        const bool more = (c + 1 < nch);
        (void)hipMemsetAsync(bar, 0, sz_bar, stream);
        lstm_fused<<<384, 256, 0, stream>>>(cur, whh1b, hA, hB, cbuf, hs0,
            clsw, emis, c * CH, CH, CH, bar,
            more ? hs0 + (size_t)(c + 1) * CH * BB * 1024 : nullptr,
            more ? hs0 + (size_t)(TT - (size_t)(c + 2) * CH) * BB * 1024 : nullptr,
            wih1b, b1, nxt, 1024, njobs);
    }

    crf_k<<<BB, 64, 0, stream>>>(y, emis, cst, cen, ctr, llh);
    final_k<<<1, 128, 0, stream>>>(llh, out);
}

// Round 7
// 4654.208 us; speedup vs baseline: 1.9552x; 1.0086x over previous
//
#include <hip/hip_runtime.h>
#include <hip/hip_bf16.h>

#define VV 30000
#define HH 512
#define NC 9
#define BB 128
#define TT 256
#define GG 2048
#define TB (TT*BB)

using short8 = __attribute__((ext_vector_type(8))) short;
using f32x4  = __attribute__((ext_vector_type(4))) float;

__device__ inline float bf2f(unsigned short u){
    union { unsigned int i; float f; } v; v.i = ((unsigned int)u) << 16; return v.f;
}
__device__ inline unsigned short f2bf(float f){
    union { unsigned int i; float f; } v; v.f = f;
    unsigned int x = v.i;
    unsigned int r = (x + 0x7fffu + ((x >> 16) & 1u)) >> 16;
    return (unsigned short)r;
}
__device__ inline float sigm(float x){
    if (x >= 0.f){ return 1.f / (1.f + __expf(-x)); }
    float e = __expf(x); return e / (1.f + e);
}
__device__ inline float tanh_f(float x){
    float ax = fabsf(x);
    float e = __expf(-2.f * ax);
    float t = (1.f - e) / (1.f + e);
    return copysignf(t, x);
}

// ---------------- weight cast fp32 -> bf16 ----------------
__global__ void castbf(const float* __restrict__ in, unsigned short* __restrict__ out, int n){
    int i = blockIdx.x * blockDim.x + threadIdx.x;
    if (i < n) out[i] = f2bf(in[i]);
}

// ---------------- embedding + renorm -> xs bf16 [T*B][H] ----------------
__global__ __launch_bounds__(256) void embed_k(const int* __restrict__ x,
                                               const float* __restrict__ embed,
                                               unsigned short* __restrict__ xs){
    int wid  = (int)((blockIdx.x * blockDim.x + threadIdx.x) >> 6);
    int lane = threadIdx.x & 63;
    if (wid >= TB) return;
    int t = wid >> 7, b = wid & 127;
    int tok = x[b * TT + t];
    const float4* e = (const float4*)(embed + (size_t)tok * HH);
    float4 v0 = e[lane], v1 = e[lane + 64];
    float ss = v0.x*v0.x + v0.y*v0.y + v0.z*v0.z + v0.w*v0.w
             + v1.x*v1.x + v1.y*v1.y + v1.z*v1.z + v1.w*v1.w;
    #pragma unroll
    for (int off = 32; off > 0; off >>= 1) ss += __shfl_xor(ss, off, 64);
    float nrm = sqrtf(ss);
    float sc = (nrm > 1.f) ? 1.f / (nrm + 1e-7f) : 1.f;
    unsigned short* dst = xs + (size_t)wid * HH;
    ushort4 o0, o1;
    o0.x = f2bf(v0.x * sc); o0.y = f2bf(v0.y * sc); o0.z = f2bf(v0.z * sc); o0.w = f2bf(v0.w * sc);
    o1.x = f2bf(v1.x * sc); o1.y = f2bf(v1.y * sc); o1.z = f2bf(v1.z * sc); o1.w = f2bf(v1.w * sc);
    ((ushort4*)dst)[lane]      = o0;
    ((ushort4*)dst)[lane + 64] = o1;
}

// ---------------- bf16 GEMM (both dirs via blockIdx.z): C = A@W^T + bias ----------------
__global__ __launch_bounds__(256) void gemm2(const unsigned short* __restrict__ A0,
                                             const unsigned short* __restrict__ A1,
                                             const unsigned short* __restrict__ Wb_,
                                             const float* __restrict__ bias,
                                             unsigned short* __restrict__ Cout,
                                             int K, int CH){
    const int dz = blockIdx.z;
    const unsigned short* A  = dz ? A1 : A0;
    const unsigned short* W  = Wb_ + (size_t)dz * GG * K;
    const float*          bd = bias + dz * GG;
    unsigned short*       C  = Cout + (size_t)dz * CH * BB * GG;

    __shared__ __align__(16) unsigned short smem[16384];

    const int tid  = threadIdx.x;
    const int lane = tid & 63;
    const int wv   = tid >> 6;
    const int l15  = lane & 15, quad = lane >> 4;
    const int mw   = (wv >> 1) * 64;
    const int nw   = (wv & 1) * 64;

    const int nwg   = gridDim.x * gridDim.y;
    const int chunk = nwg >> 3;
    const int id    = blockIdx.x + gridDim.x * blockIdx.y;
    const int nid   = (id & 7) * chunk + (id >> 3);
    const int m0    = (nid % gridDim.x) * 128;
    const int n0    = (nid / gridDim.x) * 128;

    const int srow = lane >> 2;
    const int scol = (lane & 3) * 8;
    const int c0 = wv * 2, c1 = wv * 2 + 1;
    const unsigned short* gA0 = A + (size_t)(m0 + c0 * 16 + srow) * K + scol;
    const unsigned short* gA1 = A + (size_t)(m0 + c1 * 16 + srow) * K + scol;
    const unsigned short* gB0 = W + (size_t)(n0 + c0 * 16 + srow) * K + scol;
    const unsigned short* gB1 = W + (size_t)(n0 + c1 * 16 + srow) * K + scol;

    f32x4 acc[4][4];
    #pragma unroll
    for (int i = 0; i < 4; i++)
        #pragma unroll
        for (int j = 0; j < 4; j++){ acc[i][j][0]=0.f; acc[i][j][1]=0.f; acc[i][j][2]=0.f; acc[i][j][3]=0.f; }

    #define STAGE(bufi, kko)                                                                              \
        do {                                                                                              \
            __builtin_amdgcn_global_load_lds((const __attribute__((address_space(1))) void*)(gA0 + (kko)),\
                (__attribute__((address_space(3))) void*)(smem + (bufi) * 4096 + c0 * 512), 16, 0, 0);    \
            __builtin_amdgcn_global_load_lds((const __attribute__((address_space(1))) void*)(gA1 + (kko)),\
                (__attribute__((address_space(3))) void*)(smem + (bufi) * 4096 + c1 * 512), 16, 0, 0);    \
            __builtin_amdgcn_global_load_lds((const __attribute__((address_space(1))) void*)(gB0 + (kko)),\
                (__attribute__((address_space(3))) void*)(smem + 8192 + (bufi) * 4096 + c0 * 512), 16, 0, 0);\
            __builtin_amdgcn_global_load_lds((const __attribute__((address_space(1))) void*)(gB1 + (kko)),\
                (__attribute__((address_space(3))) void*)(smem + 8192 + (bufi) * 4096 + c1 * 512), 16, 0, 0);\
        } while (0)

    const int nk = K >> 5;
    STAGE(0, 0);
    for (int t = 0; t < nk; ++t){
        const int buf = t & 1;
        const bool more = (t + 1 < nk);
        if (more){
            STAGE((t + 1) & 1, (t + 1) << 5);
            __builtin_amdgcn_sched_barrier(0);
            asm volatile("s_waitcnt vmcnt(4)" ::: "memory");
        } else {
            __builtin_amdgcn_sched_barrier(0);
            asm volatile("s_waitcnt vmcnt(0)" ::: "memory");
        }
        __builtin_amdgcn_s_barrier();
        __builtin_amdgcn_sched_barrier(0);

        short8 a[4], b[4];
        #pragma unroll
        for (int i = 0; i < 4; i++) a[i] = *(const short8*)&smem[(size_t)buf * 4096 + (mw + i * 16 + l15) * 32 + quad * 8];
        #pragma unroll
        for (int j = 0; j < 4; j++) b[j] = *(const short8*)&smem[8192 + (size_t)buf * 4096 + (nw + j * 16 + l15) * 32 + quad * 8];
        #pragma unroll
        for (int i = 0; i < 4; i++)
            #pragma unroll
            for (int j = 0; j < 4; j++)
                acc[i][j] = __builtin_amdgcn_mfma_f32_16x16x32_bf16(a[i], b[j], acc[i][j], 0, 0, 0);

        __builtin_amdgcn_sched_barrier(0);
        __builtin_amdgcn_s_barrier();
        __builtin_amdgcn_sched_barrier(0);
    }
    #undef STAGE

    #pragma unroll
    for (int i = 0; i < 4; i++){
        #pragma unroll
        for (int j = 0; j < 4; j++){
            const int ncol = nw + j * 16 + l15;
            const float bn = bd[n0 + ncol];
            #pragma unroll
            for (int r = 0; r < 4; r++){
                const int mrow = mw + i * 16 + quad * 4 + r;
                smem[mrow * 128 + ncol] = f2bf(acc[i][j][r] + bn);
            }
        }
    }
    __syncthreads();
    #pragma unroll
    for (int it = 0; it < 8; it++){
        const int ch  = it * 256 + tid;
        const int row = ch >> 4;
        const int col = (ch & 15) * 8;
        *(short8*)(C + (size_t)(m0 + row) * GG + n0 + col) = *(const short8*)&smem[row * 128 + col];
    }
}

// ---------------- fused: BiLSTM rings (blocks 0-127) + helper gemm (blocks 128+) ----------------
// Rings: round-3-verified per-wave-ring code, plus s_setprio(1) (T5: rings are
// the latency-critical role sharing CUs with throughput helper waves) and
// monotonic flags (fbase = layer*TT + t0; no per-chunk bar reset needed).
__global__ __launch_bounds__(256) void lstm_fused(const unsigned short* __restrict__ preC,
                                                  const unsigned short* __restrict__ whh,
                                                  unsigned short* __restrict__ hA,
                                                  unsigned short* __restrict__ hB,
                                                  float* __restrict__ cstate,
                                                  unsigned short* __restrict__ hs_out,
                                                  const float* __restrict__ cw,
                                                  float* __restrict__ em,
                                                  int t0, int nsteps, int CH, int fbase,
                                                  unsigned int* __restrict__ bar,
                                                  const unsigned short* __restrict__ An0,
                                                  const unsigned short* __restrict__ An1,
                                                  const unsigned short* __restrict__ Wi_,
                                                  const float* __restrict__ bias,
                                                  unsigned short* __restrict__ Cnext,
                                                  int K, int njobs){
    __shared__ __align__(16) unsigned char shm[69888];

    const int tid  = threadIdx.x;
    const int bx   = blockIdx.x;

    if (bx < 128){
        // ======== RING PATH ========
        __builtin_amdgcn_s_setprio(1);   // protect the latency-critical path from helper contention

        unsigned short (*w_s)[16][520] = (unsigned short (*)[16][520])shm;        // 66560 B
        unsigned short (*htile)[20]    = (unsigned short (*)[20])(shm + 66560);   //  2560 B
        float (*cw_s)[16]              = (float (*)[16])(shm + 69120);            //   576 B

        const int lane = tid & 63;
        const int wv   = tid >> 6;
        const int l15  = lane & 15, quad = lane >> 4;
        const int grp  = bx & 3;          // (d, mh)
        const int d    = grp >> 1;
        const int mh   = grp & 1;
        const int jc   = bx >> 2;         // 0..31
        const int m0   = mh * 64;

        // ---- stage W_hh slice into LDS (once) ----
        {
            const unsigned short* wbase = whh + (size_t)d * GG * HH;
            #pragma unroll
            for (int it = 0; it < 16; it++){
                int idx  = it * 256 + tid;
                int row  = idx >> 6;
                int col8 = idx & 63;
                int g2 = row >> 4, j2 = row & 15;
                short8 v = *(const short8*)(wbase + (size_t)(g2 * 512 + jc * 16 + j2) * HH + col8 * 8);
                *(short8*)&w_s[g2][j2][col8 * 8] = v;
            }
        }
        if (cw != nullptr && tid < NC * 16){
            int c = tid >> 4, j = tid & 15;
            cw_s[c][j] = cw[(size_t)c * 1024 + d * 512 + jc * 16 + j];
        }

        // ---- cstate -> 4 registers ----
        float csreg[4];
        #pragma unroll
        for (int rr = 0; rr < 4; rr++){
            const int gm = m0 + wv * 16 + quad * 4 + rr;
            csreg[rr] = cstate[((size_t)d * BB + gm) * HH + jc * 16 + l15];
        }

        // ---- initial preC prefetch (step 0) ----
        unsigned short pf[4][4];
        {
            const int time0 = d ? (TT - 1 - t0) : t0;
            const int slot0 = time0 & (CH - 1);
            const unsigned short* p0 = preC + (((size_t)(d * CH + slot0)) * BB + (m0 + wv * 16 + quad * 4)) * GG + jc * 16 + l15;
            #pragma unroll
            for (int rr = 0; rr < 4; rr++)
                #pragma unroll
                for (int g = 0; g < 4; g++)
                    pf[rr][g] = p0[(size_t)rr * GG + g * 512];
        }
        __syncthreads();   // w_s / cw_s visible; the only block barrier

        const size_t slabU = (size_t)grp * 8192;               // 8B units
        unsigned int* myFl  = bar + (((size_t)grp * 4 + wv) * 32 + jc) * 16;
        const unsigned int* pollFl = bar + (((size_t)grp * 4 + wv) * 32 + (lane & 31)) * 16;

        const int rowu = (wv * 16 + l15) * 4 + (quad & 1) * 2;
        const int jq   = quad >> 1;

        unsigned short pfN[4][4];

        for (int ls = 0; ls < nsteps; ls++){
            const int tt   = t0 + ls;
            const unsigned long long* srcU = (const unsigned long long*)((tt & 1) ? hB : hA) + slabU;
            unsigned long long*       dstU = (unsigned long long*)((tt & 1) ? hA : hB) + slabU + (size_t)jc * 256;

            // ---- ring wait (monotonic flags) ----
            if (ls > 0){
                const unsigned int tgt = (unsigned int)(fbase + ls);
                while (__hip_atomic_load(pollFl, __ATOMIC_RELAXED, __HIP_MEMORY_SCOPE_AGENT) < tgt)
                    __builtin_amdgcn_s_sleep(1);
                __builtin_amdgcn_fence(__ATOMIC_ACQUIRE, "workgroup");
                #pragma unroll
                for (int rr = 0; rr < 4; rr++)
                    #pragma unroll
                    for (int g = 0; g < 4; g++)
                        pf[rr][g] = pfN[rr][g];
            }

            // ---- A-fragments: direct global->reg (32 x 8B agent loads) ----
            unsigned long long afr[16][2];
            #pragma unroll
            for (int kk = 0; kk < 16; kk++){
                const unsigned long long* p = srcU + (size_t)(2 * kk + jq) * 256 + rowu;
                afr[kk][0] = __hip_atomic_load(p,     __ATOMIC_RELAXED, __HIP_MEMORY_SCOPE_AGENT);
                afr[kk][1] = __hip_atomic_load(p + 1, __ATOMIC_RELAXED, __HIP_MEMORY_SCOPE_AGENT);
            }

            // ---- MFMA: 16 kk x 4 gates ----
            f32x4 acc[4];
            #pragma unroll
            for (int g = 0; g < 4; g++){ acc[g][0]=0.f; acc[g][1]=0.f; acc[g][2]=0.f; acc[g][3]=0.f; }
            #pragma unroll
            for (int kk = 0; kk < 16; kk++){
                union { unsigned long long u[2]; short8 s; } cv;
                cv.u[0] = afr[kk][0]; cv.u[1] = afr[kk][1];
                const short8 a = cv.s;
                #pragma unroll
                for (int g = 0; g < 4; g++){
                    short8 b = *(const short8*)&w_s[g][l15][kk * 32 + quad * 8];
                    acc[g] = __builtin_amdgcn_mfma_f32_16x16x32_bf16(a, b, acc[g], 0, 0, 0);
                }
            }

            // ---- gate fusion (4 cells/lane) ----
            #pragma unroll
            for (int rr = 0; rr < 4; rr++){
                const int lr = wv * 16 + quad * 4 + rr;
                const float zi = acc[0][rr] + bf2f(pf[rr][0]);
                const float zf = acc[1][rr] + bf2f(pf[rr][1]);
                const float zg = acc[2][rr] + bf2f(pf[rr][2]);
                const float zo = acc[3][rr] + bf2f(pf[rr][3]);
                float cs = sigm(zf) * csreg[rr] + sigm(zi) * tanh_f(zg);
                csreg[rr] = cs;
                htile[lr][l15] = f2bf(sigm(zo) * tanh_f(cs));
            }
            const int trowL = lane >> 2;
            const unsigned long long hv8 = *(const unsigned long long*)&htile[wv * 16 + trowL][(lane & 3) * 4];

            // ---- producer: 512B wave store + own-drain + flag ----
            __hip_atomic_store(dstU + wv * 64 + lane, hv8, __ATOMIC_RELAXED, __HIP_MEMORY_SCOPE_AGENT);
            asm volatile("s_waitcnt vmcnt(0)" ::: "memory");
            if (lane == 0)
                __hip_atomic_store(myFl, (unsigned int)(fbase + ls + 1), __ATOMIC_RELAXED, __HIP_MEMORY_SCOPE_AGENT);

            // ---- off-critical-path (hidden under next poll) ----
            const int time = d ? (TT - 1 - tt) : tt;
            const bool more = (ls + 1 < nsteps);

            if (more){
                const int tt1 = tt + 1;
                const int time1 = d ? (TT - 1 - tt1) : tt1;
                const int slot1 = time1 & (CH - 1);
                const unsigned short* p1 = preC + (((size_t)(d * CH + slot1)) * BB + (m0 + wv * 16 + quad * 4)) * GG + jc * 16 + l15;
                #pragma unroll
                for (int rr = 0; rr < 4; rr++)
                    #pragma unroll
                    for (int g = 0; g < 4; g++)
                        pfN[rr][g] = p1[(size_t)rr * GG + g * 512];
            }

            if (cw == nullptr){
                *(unsigned long long*)(hs_out + ((size_t)time * BB + m0 + wv * 16 + trowL) * (2 * HH) + d * HH + jc * 16 + (lane & 3) * 4) = hv8;
            } else {
                const int part = lane & 3;
                float hvv[4];
                #pragma unroll
                for (int k = 0; k < 4; k++) hvv[k] = bf2f((unsigned short)(hv8 >> (16 * k)));
                float p[NC];
                #pragma unroll
                for (int c = 0; c < NC; c++){
                    float s = 0.f;
                    #pragma unroll
                    for (int k = 0; k < 4; k++) s += hvv[k] * cw_s[c][part * 4 + k];
                    p[c] = s;
                }
                #pragma unroll
                for (int c = 0; c < NC; c++){
                    p[c] += __shfl_xor(p[c], 1, 64);
                    p[c] += __shfl_xor(p[c], 2, 64);
                }
                if (part == 0){
                    float* emr = em + ((size_t)time * BB + m0 + wv * 16 + trowL) * NC;
                    #pragma unroll
                    for (int c = 0; c < NC; c++) atomicAdd(emr + c, p[c]);
                }
            }
        }

        // ---- cstate regs -> global ----
        #pragma unroll
        for (int rr = 0; rr < 4; rr++){
            const int gm = m0 + wv * 16 + quad * 4 + rr;
            cstate[((size_t)d * BB + gm) * HH + jc * 16 + l15] = csreg[rr];
        }
        return;
    }

    // ======== HELPER PATH: gemm tile-jobs for the NEXT chunk ========
    if (An0 == nullptr) return;
    unsigned short* smem = (unsigned short*)shm;   // 32 KB staging + C-bounce

    const int lane = tid & 63;
    const int wv   = tid >> 6;
    const int l15  = lane & 15, quad = lane >> 4;
    const int mw   = (wv >> 1) * 64;
    const int nw   = (wv & 1) * 64;
    const int srow = lane >> 2;
    const int scol = (lane & 3) * 8;
    const int c0 = wv * 2, c1 = wv * 2 + 1;
    const int nhb = (int)gridDim.x - 128;
    const int CHn = nsteps;

    for (int job = bx - 128; job < njobs; job += nhb){
        const int xj  = job % CHn;
        const int rem = job / CHn;
        const int yj  = rem & 15;
        const int dz  = rem >> 4;
        const unsigned short* A  = dz ? An1 : An0;
        const unsigned short* W  = Wi_ + (size_t)dz * GG * K;
        const float*          bd = bias + dz * GG;
        unsigned short*       C  = Cnext + (size_t)dz * CHn * BB * GG;
        const int m0 = xj * 128;
        const int n0 = yj * 128;

        const unsigned short* gA0 = A + (size_t)(m0 + c0 * 16 + srow) * K + scol;
        const unsigned short* gA1 = A + (size_t)(m0 + c1 * 16 + srow) * K + scol;
        const unsigned short* gB0 = W + (size_t)(n0 + c0 * 16 + srow) * K + scol;
        const unsigned short* gB1 = W + (size_t)(n0 + c1 * 16 + srow) * K + scol;

        f32x4 acc[4][4];
        #pragma unroll
        for (int i = 0; i < 4; i++)
            #pragma unroll
            for (int j = 0; j < 4; j++){ acc[i][j][0]=0.f; acc[i][j][1]=0.f; acc[i][j][2]=0.f; acc[i][j][3]=0.f; }

        #define HSTAGE(bufi, kko)                                                                             \
            do {                                                                                              \
                __builtin_amdgcn_global_load_lds((const __attribute__((address_space(1))) void*)(gA0 + (kko)),\
                    (__attribute__((address_space(3))) void*)(smem + (bufi) * 4096 + c0 * 512), 16, 0, 0);    \
                __builtin_amdgcn_global_load_lds((const __attribute__((address_space(1))) void*)(gA1 + (kko)),\
                    (__attribute__((address_space(3))) void*)(smem + (bufi) * 4096 + c1 * 512), 16, 0, 0);    \
                __builtin_amdgcn_global_load_lds((const __attribute__((address_space(1))) void*)(gB0 + (kko)),\
                    (__attribute__((address_space(3))) void*)(smem + 8192 + (bufi) * 4096 + c0 * 512), 16, 0, 0);\
                __builtin_amdgcn_global_load_lds((const __attribute__((address_space(1))) void*)(gB1 + (kko)),\
                    (__attribute__((address_space(3))) void*)(smem + 8192 + (bufi) * 4096 + c1 * 512), 16, 0, 0);\
            } while (0)

        const int nk = K >> 5;
        HSTAGE(0, 0);
        for (int t = 0; t < nk; ++t){
            const int buf = t & 1;
            const bool more = (t + 1 < nk);
            if (more){
                HSTAGE((t + 1) & 1, (t + 1) << 5);
                __builtin_amdgcn_sched_barrier(0);
                asm volatile("s_waitcnt vmcnt(4)" ::: "memory");
            } else {
                __builtin_amdgcn_sched_barrier(0);
                asm volatile("s_waitcnt vmcnt(0)" ::: "memory");
            }
            __builtin_amdgcn_s_barrier();
            __builtin_amdgcn_sched_barrier(0);

            short8 a[4], b[4];
            #pragma unroll
            for (int i = 0; i < 4; i++) a[i] = *(const short8*)&smem[(size_t)buf * 4096 + (mw + i * 16 + l15) * 32 + quad * 8];
            #pragma unroll
            for (int j = 0; j < 4; j++) b[j] = *(const short8*)&smem[8192 + (size_t)buf * 4096 + (nw + j * 16 + l15) * 32 + quad * 8];
            #pragma unroll
            for (int i = 0; i < 4; i++)
                #pragma unroll
                for (int j = 0; j < 4; j++)
                    acc[i][j] = __builtin_amdgcn_mfma_f32_16x16x32_bf16(a[i], b[j], acc[i][j], 0, 0, 0);

            __builtin_amdgcn_sched_barrier(0);
            __builtin_amdgcn_s_barrier();
            __builtin_amdgcn_sched_barrier(0);
        }
        #undef HSTAGE

        #pragma unroll
        for (int i = 0; i < 4; i++){
            #pragma unroll
            for (int j = 0; j < 4; j++){
                const int ncol = nw + j * 16 + l15;
                const float bn = bd[n0 + ncol];
                #pragma unroll
                for (int r = 0; r < 4; r++){
                    const int mrow = mw + i * 16 + quad * 4 + r;
                    smem[mrow * 128 + ncol] = f2bf(acc[i][j][r] + bn);
                }
            }
        }
        __syncthreads();
        #pragma unroll
        for (int it = 0; it < 8; it++){
            const int ch  = it * 256 + tid;
            const int row = ch >> 4;
            const int col = (ch & 15) * 8;
            *(short8*)(C + (size_t)(m0 + row) * GG + n0 + col) = *(const short8*)&smem[row * 128 + col];
        }
        __syncthreads();   // C-bounce reads done before next job's staging
    }
}

// ---------------- em init: em[t,b,c] = cls_b[c] ----------------
__global__ void eminit(const float* __restrict__ cb, float* __restrict__ em){
    int i = blockIdx.x * blockDim.x + threadIdx.x;
    if (i < TB * NC) em[i] = cb[i % NC];
}

// ---------------- CRF per-sequence ----------------
__global__ __launch_bounds__(64) void crf_k(const int* __restrict__ y,
                                            const float* __restrict__ em,
                                            const float* __restrict__ cstart,
                                            const float* __restrict__ cend,
                                            const float* __restrict__ ctr,
                                            float* __restrict__ llh){
    int b = blockIdx.x;
    int lane = threadIdx.x;

    float sp = 0.f; int cnt = 0;
    for (int t = lane; t < TT; t += 64){
        int yt = y[b * TT + t];
        bool mk = (yt > -1);
        cnt += mk ? 1 : 0;
        if (t >= 1 && mk){
            int yp  = y[b * TT + t - 1];
            int tag  = yt > 0 ? yt : 0;
            int tagp = yp > 0 ? yp : 0;
            sp += ctr[tagp * NC + tag] + em[((size_t)t * BB + b) * NC + tag];
        }
    }
    #pragma unroll
    for (int off = 32; off > 0; off >>= 1){
        sp  += __shfl_xor(sp, off, 64);
        cnt += __shfl_xor(cnt, off, 64);
    }

    float trc[NC];
    #pragma unroll
    for (int cc2 = 0; cc2 < NC; cc2++) trc[cc2] = 0.f;
    if (lane < NC){
        #pragma unroll
        for (int cc2 = 0; cc2 < NC; cc2++) trc[cc2] = ctr[cc2 * NC + lane];
    }
    float alpha = -1e30f;
    if (lane < NC) alpha = cstart[lane] + em[(size_t)b * NC + lane];

    for (int t = 1; t < TT; t++){
        int yt = y[b * TT + t];
        bool mk = (yt > -1);
        float e = (lane < NC) ? em[((size_t)t * BB + b) * NC + lane] : 0.f;
        float v[NC]; float mx = -1e30f;
        #pragma unroll
        for (int cc2 = 0; cc2 < NC; cc2++){
            float ac = __shfl(alpha, cc2, 64);
            v[cc2] = ac + trc[cc2];
            mx = fmaxf(mx, v[cc2]);
        }
        float s = 0.f;
        #pragma unroll
        for (int cc2 = 0; cc2 < NC; cc2++) s += __expf(v[cc2] - mx);
        float nxt = mx + __logf(s) + e;
        if (mk && lane < NC) alpha = nxt;
    }

    float val = (lane < NC) ? (alpha + cend[lane]) : -1e30f;
    float mx = -1e30f;
    #pragma unroll
    for (int cc2 = 0; cc2 < NC; cc2++) mx = fmaxf(mx, __shfl(val, cc2, 64));
    float s = 0.f;
    #pragma unroll
    for (int cc2 = 0; cc2 < NC; cc2++) s += __expf(__shfl(val, cc2, 64) - mx);
    float denom = mx + __logf(s);

    if (lane == 0){
        int y0 = y[b * TT];
        int tag0 = y0 > 0 ? y0 : 0;
        int se = cnt - 1;
        if (se < 0) se = 0;
        int yl = y[b * TT + se];
        int tagl = yl > 0 ? yl : 0;
        float score = sp + cstart[tag0] + em[(size_t)b * NC + tag0] + cend[tagl];
        llh[b] = score - denom;
    }
}

__global__ void final_k(const float* __restrict__ llh, float* __restrict__ out){
    __shared__ float sm[128];
    int i = threadIdx.x;
    sm[i] = llh[i];
    __syncthreads();
    for (int s = 64; s > 0; s >>= 1){
        if (i < s) sm[i] += sm[i + s];
        __syncthreads();
    }
    if (i == 0) out[0] = -sm[0] / 128.f;
}

__global__ void sentinel_k(float* out, float v){ out[0] = v; }

extern "C" void kernel_launch(void* const* d_in, const int* in_sizes, int n_in,
                              void* d_out, int out_size, void* d_ws, size_t ws_size,
                              hipStream_t stream) {
    const int*   x     = (const int*)d_in[0];
    const int*   y     = (const int*)d_in[1];
    const float* embed = (const float*)d_in[2];
    const float* wih0  = (const float*)d_in[3];
    const float* whh0  = (const float*)d_in[4];
    const float* b0    = (const float*)d_in[5];
    const float* wih1  = (const float*)d_in[6];
    const float* whh1  = (const float*)d_in[7];
    const float* b1    = (const float*)d_in[8];
    const float* clsw  = (const float*)d_in[9];
    const float* clsb  = (const float*)d_in[10];
    const float* cst   = (const float*)d_in[11];
    const float* cen   = (const float*)d_in[12];
    const float* ctr   = (const float*)d_in[13];
    float* out = (float*)d_out;

    const size_t sz_w0   = (size_t)2 * GG * HH * 2;
    const size_t sz_w1   = (size_t)2 * GG * 1024 * 2;
    const size_t sz_xs   = (size_t)TB * HH * 2;
    const size_t sz_hs0  = (size_t)TB * 1024 * 2;
    const size_t sz_h    = (size_t)2 * BB * HH * 2;
    const size_t sz_c    = (size_t)2 * BB * HH * 4;
    const size_t sz_emis = (size_t)TB * NC * 4;
    const size_t sz_llh  = (size_t)BB * 4;
    const size_t sz_bar  = 32768;
    auto rup = [](size_t v){ return (v + 255) & ~(size_t)255; };
    size_t fixed = rup(sz_w0) * 3 + rup(sz_w1) + rup(sz_xs) + rup(sz_hs0)
                 + rup(sz_h) * 2 + rup(sz_c) + rup(sz_emis) + rup(sz_llh) + rup(sz_bar);

    const int cands[5] = {128, 64, 32, 16, 8};
    int CH = 0;
    for (int i = 0; i < 5; i++){
        size_t par = (size_t)2 * cands[i] * BB * GG * 2;
        if (fixed + 2 * rup(par) <= ws_size){ CH = cands[i]; break; }
    }
    if (CH == 0){
        sentinel_k<<<1, 1, 0, stream>>>(out, -(float)(ws_size >> 20));
        return;
    }
    const size_t parSz = (size_t)2 * CH * BB * GG * 2;

    char* ws = (char*)d_ws;
    size_t off = 0;
    auto alloc = [&](size_t bytes) -> void* {
        void* p = (void*)(ws + off);
        off += (bytes + 255) & ~(size_t)255;
        return p;
    };
    unsigned short* wih0b = (unsigned short*)alloc(sz_w0);
    unsigned short* whh0b = (unsigned short*)alloc(sz_w0);
    unsigned short* whh1b = (unsigned short*)alloc(sz_w0);
    unsigned short* wih1b = (unsigned short*)alloc(sz_w1);
    unsigned short* xs    = (unsigned short*)alloc(sz_xs);
    unsigned short* hs0   = (unsigned short*)alloc(sz_hs0);
    unsigned short* hA    = (unsigned short*)alloc(sz_h);
    unsigned short* hB    = (unsigned short*)alloc(sz_h);
    float*          cbuf  = (float*)alloc(sz_c);
    float*          emis  = (float*)alloc(sz_emis);
    float*          llh   = (float*)alloc(sz_llh);
    unsigned int*   bar   = (unsigned int*)alloc(sz_bar);
    unsigned short* preC0 = (unsigned short*)alloc(parSz);
    unsigned short* preC1 = (unsigned short*)alloc(parSz);

    castbf<<<(2 * GG * HH + 255) / 256, 256, 0, stream>>>(wih0, wih0b, 2 * GG * HH);
    castbf<<<(2 * GG * HH + 255) / 256, 256, 0, stream>>>(whh0, whh0b, 2 * GG * HH);
    castbf<<<(2 * GG * 1024 + 255) / 256, 256, 0, stream>>>(wih1, wih1b, 2 * GG * 1024);
    castbf<<<(2 * GG * HH + 255) / 256, 256, 0, stream>>>(whh1, whh1b, 2 * GG * HH);

    embed_k<<<TB / 4, 256, 0, stream>>>(x, embed, xs);
    (void)hipMemsetAsync(bar, 0, sz_bar, stream);   // once per launch: flags are monotonic

    const int nch = TT / CH;
    const int njobs = CH * 16 * 2;

    // ---------- emissions init (before any layer-1 atomics) ----------
    eminit<<<(TB * NC + 255) / 256, 256, 0, stream>>>(clsb, emis);

    // ---------- layer 0 (writes hs0) ----------
    (void)hipMemsetAsync(hA, 0, sz_h, stream);
    (void)hipMemsetAsync(cbuf, 0, sz_c, stream);
    gemm2<<<dim3(CH, GG / 128, 2), 256, 0, stream>>>(
        xs, xs + (size_t)(TT - CH) * BB * HH, wih0b, b0, preC0, HH, CH);
    for (int c = 0; c < nch; c++){
        unsigned short* cur = (c & 1) ? preC1 : preC0;
        unsigned short* nxt = (c & 1) ? preC0 : preC1;
        const bool more = (c + 1 < nch);
        lstm_fused<<<more ? 512 : 128, 256, 0, stream>>>(cur, whh0b, hA, hB, cbuf, hs0,
            nullptr, emis, c * CH, CH, CH, c * CH, bar,
            more ? xs + (size_t)(c + 1) * CH * BB * HH : nullptr,
            more ? xs + (size_t)(TT - (size_t)(c + 2) * CH) * BB * HH : nullptr,
            wih0b, b0, nxt, HH, njobs);
    }

    // ---------- layer 1 (fused emissions, no hs1) ----------
    (void)hipMemsetAsync(hA, 0, sz_h, stream);
    (void)hipMemsetAsync(cbuf, 0, sz_c, stream);
    gemm2<<<dim3(CH, GG / 128, 2), 256, 0, stream>>>(
        hs0, hs0 + (size_t)(TT - CH) * BB * 1024, wih1b, b1, preC0, 1024, CH);
    for (int c = 0; c < nch; c++){
        unsigned short* cur = (c & 1) ? preC1 : preC0;
        unsigned short* nxt = (c & 1) ? preC0 : preC1;
        const bool more = (c + 1 < nch);
        lstm_fused<<<more ? 512 : 128, 256, 0, stream>>>(cur, whh1b, hA, hB, cbuf, hs0,
            clsw, emis, c * CH, CH, CH, TT + c * CH, bar,
            more ? hs0 + (size_t)(c + 1) * CH * BB * 1024 : nullptr,
            more ? hs0 + (size_t)(TT - (size_t)(c + 2) * CH) * BB * 1024 : nullptr,
            wih1b, b1, nxt, 1024, njobs);
    }

    crf_k<<<BB, 64, 0, stream>>>(y, emis, cst, cen, ctr, llh);
    final_k<<<1, 128, 0, stream>>>(llh, out);
}